// Round 5
// baseline (1529.776 us; speedup 1.0000x reference)
//
#include <hip/hip_runtime.h>
#include <type_traits>

#define N_NODES 100000
#define N_EDGES 1600000
#define NFEAT 512
#define NHID 256
#define NCLASS 40
#define NPAD 100096   // 391 * 256

// bucket sort geometry
#define NBUCK 196     // buckets of 512 rows
#define BROWS 512
#define NBLK_BIN 256
#define EPB 6250      // 256 * 6250 == 1,600,000 exactly

// class split: 40 = 16 (C) + 16 (D) + 8 (B). Each group's v-buffer is
// 3.2 / 3.2 / 1.6 MB -> L2-resident per XCD. XCD partition: C on xcd 0-2,
// D on 3-5, B on 6-7 (blockIdx & 7 ~ XCD round-robin on MI355X).
#define CBLK 6250     // 25,000 waves x 4 rows (CW=16)
#define BBLK 3125     // 12,500 waves x 8 rows (CW=8)
#define GRID_SPMM 16672  // 2084 rounds * 8 xcd slots

typedef __bf16 bf16;
typedef __bf16 bf16x8 __attribute__((ext_vector_type(8)));
typedef float f32x4 __attribute__((ext_vector_type(4)));

// ---------------- CSR build via 2-level counting sort ----------------

__global__ __launch_bounds__(256) void bin_count(const int* __restrict__ rows,
                                                 int* __restrict__ bcnt) {
    __shared__ int hist[NBUCK];
    int t = threadIdx.x, b = blockIdx.x;
    for (int i = t; i < NBUCK; i += 256) hist[i] = 0;
    __syncthreads();
    int base = b * EPB;
    for (int i = t; i < EPB; i += 256) atomicAdd(&hist[rows[base + i] >> 9], 1);
    __syncthreads();
    for (int i = t; i < NBUCK; i += 256) bcnt[i * NBLK_BIN + b] = hist[i];
}

__global__ __launch_bounds__(256) void bin_scan(const int* __restrict__ bcnt,
                                                int* __restrict__ boff2,
                                                int* __restrict__ btot) {
    __shared__ int sh[256];
    int t = threadIdx.x, bu = blockIdx.x;
    int v = bcnt[bu * 256 + t];
    sh[t] = v;
    __syncthreads();
    for (int off = 1; off < 256; off <<= 1) {
        int x = (t >= off) ? sh[t - off] : 0;
        __syncthreads();
        sh[t] += x;
        __syncthreads();
    }
    boff2[t * NBUCK + bu] = sh[t] - v;  // exclusive, [block][bucket] layout
    if (t == 255) btot[bu] = sh[255];
}

__global__ __launch_bounds__(256) void base_scan(const int* __restrict__ btot,
                                                 int* __restrict__ bbase) {
    __shared__ int sh[256];
    int t = threadIdx.x;
    int v = (t < NBUCK) ? btot[t] : 0;
    sh[t] = v;
    __syncthreads();
    for (int off = 1; off < 256; off <<= 1) {
        int x = (t >= off) ? sh[t - off] : 0;
        __syncthreads();
        sh[t] += x;
        __syncthreads();
    }
    if (t < NBUCK) bbase[t] = sh[t] - v;
    if (t == NBUCK - 1) bbase[NBUCK] = sh[t];  // == N_EDGES
}

__global__ __launch_bounds__(256) void bin_scatter(const int* __restrict__ rows,
                                                   const int* __restrict__ cols,
                                                   const int* __restrict__ boff2,
                                                   const int* __restrict__ bbase,
                                                   int* __restrict__ binned) {
    __shared__ int cur[NBUCK];
    int t = threadIdx.x, b = blockIdx.x;
    for (int i = t; i < NBUCK; i += 256) cur[i] = bbase[i] + boff2[b * NBUCK + i];
    __syncthreads();
    int base = b * EPB;
    for (int i = t; i < EPB; i += 256) {
        int r = rows[base + i], c = cols[base + i];
        int pos = atomicAdd(&cur[r >> 9], 1);
        binned[pos] = ((r & 511) << 17) | c;  // col < 100000 < 2^17
    }
}

__global__ __launch_bounds__(256) void bucket_csr(const int* __restrict__ binned,
                                                  const int* __restrict__ bbase,
                                                  int* __restrict__ rowptr,
                                                  int* __restrict__ colidx,
                                                  float* __restrict__ dinv) {
    __shared__ int cnt[BROWS];
    __shared__ int pref[BROWS];
    __shared__ int psum[256];
    int t = threadIdx.x, bu = blockIdx.x;
    cnt[t] = 0;
    cnt[t + 256] = 0;
    __syncthreads();
    int base = bbase[bu], end = bbase[bu + 1];
    for (int i = base + t; i < end; i += 256) atomicAdd(&cnt[binned[i] >> 17], 1);
    __syncthreads();
    int c0 = cnt[2 * t], c1 = cnt[2 * t + 1];
    psum[t] = c0 + c1;
    __syncthreads();
    for (int off = 1; off < 256; off <<= 1) {
        int x = (t >= off) ? psum[t - off] : 0;
        __syncthreads();
        psum[t] += x;
        __syncthreads();
    }
    int pex = psum[t] - (c0 + c1);
    pref[2 * t] = pex;
    pref[2 * t + 1] = pex + c0;
    __syncthreads();
#pragma unroll
    for (int j = 0; j < 2; j++) {
        int idx = t + j * 256;
        int grow = bu * BROWS + idx;
        if (grow < N_NODES) {
            rowptr[grow] = base + pref[idx];
            dinv[grow] = 0.5f / (float)(cnt[idx] + 1);  // pre-halved, +1 self-loop
        } else if (grow == N_NODES) {
            rowptr[N_NODES] = N_EDGES;
        }
        pref[idx] += base;  // absolute cursor
    }
    __syncthreads();
    for (int i = base + t; i < end; i += 256) {
        int v = binned[i];
        int pos = atomicAdd(&pref[v >> 17], 1);
        colidx[pos] = v & 0x1FFFF;  // raw col
    }
}

// ---------------- weight conversion ----------------

__global__ void cvt_f2b(const float* __restrict__ a, bf16* __restrict__ b, int n) {
    int i = blockIdx.x * 256 + threadIdx.x;
    if (i < n) b[i] = (bf16)a[i];
}

__global__ void pad_w3(const float* __restrict__ W3, const float* __restrict__ b3,
                       bf16* __restrict__ W3p, float* __restrict__ b3p) {
    int i = blockIdx.x * 256 + threadIdx.x;  // over 64*256
    int r = i >> 8;
    W3p[i] = (bf16)((r < NCLASS) ? W3[(size_t)r * 256 + (i & 255)] : 0.f);
    if (i < 64) b3p[i] = (i < NCLASS) ? b3[i] : 0.f;
}

// zero the dummy gather rows (index N_NODES) in all v buffers
__global__ void zero_dummy(bf16* vCi, bf16* vC0, bf16* vC1,
                           bf16* vDi, bf16* vD0, bf16* vD1,
                           bf16* vBi, bf16* vB0, bf16* vB1) {
    int i = threadIdx.x;
    if (i < 16) {
        vCi[(size_t)N_NODES * 16 + i] = (bf16)0.f;
        vC0[(size_t)N_NODES * 16 + i] = (bf16)0.f;
        vC1[(size_t)N_NODES * 16 + i] = (bf16)0.f;
        vDi[(size_t)N_NODES * 16 + i] = (bf16)0.f;
        vD0[(size_t)N_NODES * 16 + i] = (bf16)0.f;
        vD1[(size_t)N_NODES * 16 + i] = (bf16)0.f;
    }
    if (i < 8) {
        vBi[(size_t)N_NODES * 8 + i] = (bf16)0.f;
        vB0[(size_t)N_NODES * 8 + i] = (bf16)0.f;
        vB1[(size_t)N_NODES * 8 + i] = (bf16)0.f;
    }
}

// ---------------- no-LDS direct-fragment MFMA GEMM-NT ----------------
// C[M, WN*64] = A[M,KT] @ B[WN*64,KT]^T + bias. Fragments loaded straight
// from global (B is L2-resident; A rows shared across waves via L1/L2).
// No LDS, no barriers. WN waves along N, 4/WN along M; 64 rows per wave.
// OUTMODE 0: bf16 out. OUTMODE 1: class-split h (fp32, pre-halved) + v0 (bf16).

template <int WN, int KT, typename AT, bool RELU, int OUTMODE>
__global__ __launch_bounds__(256) void gemm_direct(const AT* __restrict__ A,
                                                   const bf16* __restrict__ B,
                                                   const float* __restrict__ bias,
                                                   bf16* __restrict__ Cb,
                                                   float* __restrict__ hC,
                                                   float* __restrict__ hD,
                                                   float* __restrict__ hB8,
                                                   bf16* __restrict__ vC0,
                                                   bf16* __restrict__ vD0,
                                                   bf16* __restrict__ vB0,
                                                   int M) {
    constexpr int WM = 4 / WN;
    constexpr bool AF32 = std::is_same<AT, float>::value;
    constexpr int NT = KT / 32;
    const int Nout = WN * 64;

    int wave = threadIdx.x >> 6, lane = threadIdx.x & 63;
    int waveN = wave % WN, waveM = wave / WN;
    int lc = lane & 15, lq = lane >> 4;
    int rbase = blockIdx.x * (WM * 64) + waveM * 64;

    const AT* ap[4];
    const bf16* bp[4];
#pragma unroll
    for (int i = 0; i < 4; i++) {
        int r = rbase + i * 16 + lc;
        if (r > M - 1) r = M - 1;  // clamp: OOB rows computed then discarded
        ap[i] = A + (size_t)r * KT + lq * 8;
        bp[i] = B + (size_t)(waveN * 64 + i * 16 + lc) * KT + lq * 8;
    }

    f32x4 acc[4][4];
#pragma unroll
    for (int i = 0; i < 4; i++)
#pragma unroll
        for (int j = 0; j < 4; j++) acc[i][j] = (f32x4){0.f, 0.f, 0.f, 0.f};

#pragma unroll
    for (int t = 0; t < NT; t++) {
        int k0 = t * 32;
        bf16x8 af[4], bfr[4];
#pragma unroll
        for (int j = 0; j < 4; j++) bfr[j] = *(const bf16x8*)(bp[j] + k0);
#pragma unroll
        for (int i = 0; i < 4; i++) {
            if constexpr (AF32) {
                float4 q0 = *(const float4*)(ap[i] + k0);
                float4 q1 = *(const float4*)(ap[i] + k0 + 4);
                af[i][0] = (bf16)q0.x; af[i][1] = (bf16)q0.y;
                af[i][2] = (bf16)q0.z; af[i][3] = (bf16)q0.w;
                af[i][4] = (bf16)q1.x; af[i][5] = (bf16)q1.y;
                af[i][6] = (bf16)q1.z; af[i][7] = (bf16)q1.w;
            } else {
                af[i] = *(const bf16x8*)(ap[i] + k0);
            }
        }
#pragma unroll
        for (int i = 0; i < 4; i++)
#pragma unroll
            for (int j = 0; j < 4; j++)
                acc[i][j] = __builtin_amdgcn_mfma_f32_16x16x32_bf16(af[i], bfr[j], acc[i][j], 0, 0, 0);
    }

    // epilogue
#pragma unroll
    for (int i = 0; i < 4; i++) {
        int row0 = rbase + i * 16 + lq * 4;
#pragma unroll
        for (int j = 0; j < 4; j++) {
            int col = waveN * 64 + j * 16 + lc;
            float bv = bias[col];
#pragma unroll
            for (int reg = 0; reg < 4; reg++) {
                int rr = row0 + reg;
                if (rr < M) {
                    float v = acc[i][j][reg] + bv;
                    if (RELU) v = v > 0.f ? v : 0.f;
                    if (OUTMODE == 0) {
                        Cb[(size_t)rr * Nout + col] = (bf16)v;
                    } else {
                        if (col < 16) {
                            hC[(size_t)rr * 16 + col] = 0.5f * v;
                            vC0[(size_t)rr * 16 + col] = (bf16)v;
                        } else if (col < 32) {
                            hD[(size_t)rr * 16 + (col - 16)] = 0.5f * v;
                            vD0[(size_t)rr * 16 + (col - 16)] = (bf16)v;
                        } else if (col < NCLASS) {
                            hB8[(size_t)rr * 8 + (col - 32)] = 0.5f * v;
                            vB0[(size_t)rr * 8 + (col - 32)] = (bf16)v;
                        }
                    }
                }
            }
        }
    }
}

// ---------------- XCD-partitioned class-split power-iteration SpMM ----------------
// CW classes per group; 64/CW rows per wave. v reads cached (L2-resident per
// XCD); all streamed operands nontemporal so they never evict v.

template <int CW>
__device__ __forceinline__ void spmm_body(int wblk, const bf16* __restrict__ v,
                                          const float* __restrict__ h,
                                          const int* __restrict__ rowptr,
                                          const int* __restrict__ colidx,
                                          const float* __restrict__ dinv,
                                          bf16* __restrict__ o,
                                          float* __restrict__ outF,
                                          int obase, int final_it, int tid) {
    constexpr int RPW = 64 / CW;
    constexpr int ZOFFE = N_NODES * CW;
    int lane = tid & 63;
    int w = wblk * 4 + (tid >> 6);
    int cls = lane & (CW - 1);
    int r = w * RPW + (lane / CW);
    int s = __builtin_nontemporal_load(rowptr + r);
    int e = __builtin_nontemporal_load(rowptr + r + 1);
    int d = e - s;
    int m = d;
#pragma unroll
    for (int off = CW; off < 64; off <<= 1) {
        int x = __shfl_xor(m, off);
        m = m > x ? m : x;
    }
    float hv = __builtin_nontemporal_load(h + (size_t)r * CW + cls);  // pre-halved
    float dv = __builtin_nontemporal_load(dinv + r);
    float a0 = (float)v[(size_t)r * CW + cls];  // self-loop
    float a1 = 0.f, a2 = 0.f, a3 = 0.f, a4 = 0.f, a5 = 0.f, a6 = 0.f, a7 = 0.f;
    for (int i = 0; i < m; i += 8) {
        int o0 = (i + 0 < d) ? __builtin_nontemporal_load(colidx + s + i + 0) * CW : ZOFFE;
        int o1 = (i + 1 < d) ? __builtin_nontemporal_load(colidx + s + i + 1) * CW : ZOFFE;
        int o2 = (i + 2 < d) ? __builtin_nontemporal_load(colidx + s + i + 2) * CW : ZOFFE;
        int o3 = (i + 3 < d) ? __builtin_nontemporal_load(colidx + s + i + 3) * CW : ZOFFE;
        int o4 = (i + 4 < d) ? __builtin_nontemporal_load(colidx + s + i + 4) * CW : ZOFFE;
        int o5 = (i + 5 < d) ? __builtin_nontemporal_load(colidx + s + i + 5) * CW : ZOFFE;
        int o6 = (i + 6 < d) ? __builtin_nontemporal_load(colidx + s + i + 6) * CW : ZOFFE;
        int o7 = (i + 7 < d) ? __builtin_nontemporal_load(colidx + s + i + 7) * CW : ZOFFE;
        a0 += (float)v[(size_t)o0 + cls];
        a1 += (float)v[(size_t)o1 + cls];
        a2 += (float)v[(size_t)o2 + cls];
        a3 += (float)v[(size_t)o3 + cls];
        a4 += (float)v[(size_t)o4 + cls];
        a5 += (float)v[(size_t)o5 + cls];
        a6 += (float)v[(size_t)o6 + cls];
        a7 += (float)v[(size_t)o7 + cls];
    }
    float res = dv * (((a0 + a1) + (a2 + a3)) + ((a4 + a5) + (a6 + a7))) + hv;
    if (final_it) {
        outF[(size_t)r * NCLASS + obase + cls] = res;
    } else {
        union { bf16 b; unsigned short u; } cv;
        cv.b = (bf16)res;
        __builtin_nontemporal_store(cv.u, (unsigned short*)(o + (size_t)r * CW + cls));
    }
}

__global__ __launch_bounds__(256) void spmm_fused(
    const bf16* __restrict__ vC, const bf16* __restrict__ vD, const bf16* __restrict__ vB,
    const float* __restrict__ hC, const float* __restrict__ hD, const float* __restrict__ hB,
    const int* __restrict__ rowptr, const int* __restrict__ colidx,
    const float* __restrict__ dinv,
    bf16* __restrict__ oC, bf16* __restrict__ oD, bf16* __restrict__ oB,
    float* __restrict__ outF, int final_it) {
    int bid = blockIdx.x;
    int xcd = bid & 7;   // MI355X round-robin block->XCD (perf heuristic only)
    int rank = bid >> 3;
    int tid = threadIdx.x;
    if (xcd < 3) {
        int lb = rank * 3 + xcd;
        if (lb < CBLK)
            spmm_body<16>(lb, vC, hC, rowptr, colidx, dinv, oC, outF, 0, final_it, tid);
    } else if (xcd < 6) {
        int lb = rank * 3 + (xcd - 3);
        if (lb < CBLK)
            spmm_body<16>(lb, vD, hD, rowptr, colidx, dinv, oD, outF, 16, final_it, tid);
    } else {
        int lb = rank * 2 + (xcd - 6);
        if (lb < BBLK)
            spmm_body<8>(lb, vB, hB, rowptr, colidx, dinv, oB, outF, 32, final_it, tid);
    }
}

// ---------------- launch ----------------

extern "C" void kernel_launch(void* const* d_in, const int* in_sizes, int n_in,
                              void* d_out, int out_size, void* d_ws, size_t ws_size,
                              hipStream_t stream) {
    const float* x  = (const float*)d_in[0];
    const int*   ei = (const int*)d_in[1];
    const float* W1 = (const float*)d_in[2];
    const float* b1 = (const float*)d_in[3];
    const float* W2 = (const float*)d_in[4];
    const float* b2 = (const float*)d_in[5];
    const float* W3 = (const float*)d_in[6];
    const float* b3 = (const float*)d_in[7];
    float* out = (float*)d_out;
    const int* rows = ei;
    const int* cols = ei + N_EDGES;

    // workspace carve (bytes)
    char* p = (char*)d_ws;
    bf16* hid1 = (bf16*)p;                 p += (size_t)N_NODES * NHID * 2;       // 51.2 MB (alias: binned)
    bf16* hid2 = (bf16*)p;                 p += (size_t)N_NODES * NHID * 2;       // 51.2 MB
    float* hC  = (float*)p;                p += (size_t)N_NODES * 16 * 4;         // 6.4 MB
    float* hD  = (float*)p;                p += (size_t)N_NODES * 16 * 4;         // 6.4 MB
    float* hB8 = (float*)p;                p += (size_t)N_NODES * 8 * 4;          // 3.2 MB
    bf16* vCi  = (bf16*)p;                 p += (size_t)(N_NODES + 1) * 16 * 2;   // 3.2 MB
    bf16* vC0  = (bf16*)p;                 p += (size_t)(N_NODES + 1) * 16 * 2;
    bf16* vC1  = (bf16*)p;                 p += (size_t)(N_NODES + 1) * 16 * 2;
    bf16* vDi  = (bf16*)p;                 p += (size_t)(N_NODES + 1) * 16 * 2;
    bf16* vD0  = (bf16*)p;                 p += (size_t)(N_NODES + 1) * 16 * 2;
    bf16* vD1  = (bf16*)p;                 p += (size_t)(N_NODES + 1) * 16 * 2;
    bf16* vBi  = (bf16*)p;                 p += (size_t)(N_NODES + 1) * 8 * 2;    // 1.6 MB
    bf16* vB0  = (bf16*)p;                 p += (size_t)(N_NODES + 1) * 8 * 2;
    bf16* vB1  = (bf16*)p;                 p += (size_t)(N_NODES + 1) * 8 * 2;
    bf16* W1b  = (bf16*)p;                 p += (size_t)NHID * NFEAT * 2;
    bf16* W2b  = (bf16*)p;                 p += (size_t)NHID * NHID * 2;
    bf16* W3p  = (bf16*)p;                 p += (size_t)64 * NHID * 2;
    float* b3p = (float*)p;                p += 64 * 4;
    int* bcnt   = (int*)p;                 p += (size_t)NPAD * 4;
    int* rowptr = (int*)p;                 p += (size_t)(NPAD + 1) * 4;
    int* boff2  = (int*)p;                 p += (size_t)N_NODES * 4;
    int* colidx = (int*)p;                 p += (size_t)(N_EDGES + 64) * 4;
    int* bsum   = (int*)p;                 p += 512 * 4;
    float* dinv = (float*)p;               p += (size_t)N_NODES * 4;

    int* btot  = bsum;          // 196 ints
    int* bbase = bsum + 256;    // 197 ints
    int* binned = (int*)hid1;   // 6.4 MB, dead before MLP starts

    // CSR build
    bin_count<<<NBLK_BIN, 256, 0, stream>>>(rows, bcnt);
    bin_scan<<<NBUCK, 256, 0, stream>>>(bcnt, boff2, btot);
    base_scan<<<1, 256, 0, stream>>>(btot, bbase);
    bin_scatter<<<NBLK_BIN, 256, 0, stream>>>(rows, cols, boff2, bbase, binned);
    bucket_csr<<<NBUCK, 256, 0, stream>>>(binned, bbase, rowptr, colidx, dinv);

    // weight conversion
    cvt_f2b<<<(NHID * NFEAT + 255) / 256, 256, 0, stream>>>(W1, W1b, NHID * NFEAT);
    cvt_f2b<<<(NHID * NHID + 255) / 256, 256, 0, stream>>>(W2, W2b, NHID * NHID);
    pad_w3<<<(64 * NHID) / 256, 256, 0, stream>>>(W3, b3, W3p, b3p);

    // MLP, no-LDS direct GEMMs
    {
        int M = N_NODES;
        gemm_direct<4, 512, float, true, 0><<<(M + 63) / 64, 256, 0, stream>>>(
            x, W1b, b1, hid1, nullptr, nullptr, nullptr, nullptr, nullptr, nullptr, M);
        gemm_direct<4, 256, bf16, true, 0><<<(M + 63) / 64, 256, 0, stream>>>(
            hid1, W2b, b2, hid2, nullptr, nullptr, nullptr, nullptr, nullptr, nullptr, M);
        gemm_direct<1, 256, bf16, false, 1><<<(M + 255) / 256, 256, 0, stream>>>(
            hid2, W3p, b3p, nullptr, hC, hD, hB8, vCi, vDi, vBi, M);
    }

    zero_dummy<<<1, 64, 0, stream>>>(vCi, vC0, vC1, vDi, vD0, vD1, vBi, vB0, vB1);

    // 10 power iterations, XCD-partitioned class groups (16/16/8), one launch each
    const bf16* sC = vCi;
    const bf16* sD = vDi;
    const bf16* sB = vBi;
    for (int it = 0; it < 10; it++) {
        int fin = (it == 9);
        bf16* dC = (it & 1) ? vC1 : vC0;
        bf16* dD = (it & 1) ? vD1 : vD0;
        bf16* dB = (it & 1) ? vB1 : vB0;
        spmm_fused<<<GRID_SPMM, 256, 0, stream>>>(
            sC, sD, sB, hC, hD, hB8, rowptr, colidx, dinv, dC, dD, dB, out, fin);
        sC = dC;
        sD = dD;
        sB = dB;
    }
}

// Round 6
// 1153.752 us; speedup vs baseline: 1.3259x; 1.3259x over previous
//
#include <hip/hip_runtime.h>
#include <type_traits>

#define N_NODES 100000
#define N_EDGES 1600000
#define NFEAT 512
#define NHID 256
#define NCLASS 40
#define NPAD 100096   // 391 * 256

// bucket sort geometry
#define NBUCK 196     // buckets of 512 rows: (99999>>9)=195 -> 196 buckets
#define BROWS 512
#define NBLK_BIN 256
#define EPB 6250      // 256 * 6250 == 1,600,000 exactly

// col tiling for spmm gather locality: tile = col>>15 (4 tiles x <=32768 nodes,
// 2 MB of v per tile in pass A -> L2-resident per XCD)
#define NTILE 4

// class-split power iteration: 40 = 32 (pass A) + 8 (pass B)
#define ZA (N_NODES * 32)   // dummy zero-row element offset, pass A
#define ZB (N_NODES * 8)    // dummy zero-row element offset, pass B
#define BLK_A 12500         // 50,000 waves x 2 rows
#define BLK_B 3125          // 12,500 waves x 8 rows

typedef __bf16 bf16;
typedef __bf16 bf16x8 __attribute__((ext_vector_type(8)));
typedef float f32x4 __attribute__((ext_vector_type(4)));

// ---------------- CSR build via 2-level counting sort ----------------

__global__ __launch_bounds__(256) void bin_count(const int* __restrict__ rows,
                                                 int* __restrict__ bcnt) {
    __shared__ int hist[NBUCK];
    int t = threadIdx.x, b = blockIdx.x;
    for (int i = t; i < NBUCK; i += 256) hist[i] = 0;
    __syncthreads();
    int base = b * EPB;
    for (int i = t; i < EPB; i += 256) atomicAdd(&hist[rows[base + i] >> 9], 1);
    __syncthreads();
    for (int i = t; i < NBUCK; i += 256) bcnt[i * NBLK_BIN + b] = hist[i];
}

__global__ __launch_bounds__(256) void bin_scan(const int* __restrict__ bcnt,
                                                int* __restrict__ boff2,
                                                int* __restrict__ btot) {
    __shared__ int sh[256];
    int t = threadIdx.x, bu = blockIdx.x;
    int v = bcnt[bu * 256 + t];
    sh[t] = v;
    __syncthreads();
    for (int off = 1; off < 256; off <<= 1) {
        int x = (t >= off) ? sh[t - off] : 0;
        __syncthreads();
        sh[t] += x;
        __syncthreads();
    }
    boff2[t * NBUCK + bu] = sh[t] - v;  // exclusive, [block][bucket] layout
    if (t == 255) btot[bu] = sh[255];
}

__global__ __launch_bounds__(256) void base_scan(const int* __restrict__ btot,
                                                 int* __restrict__ bbase) {
    __shared__ int sh[256];
    int t = threadIdx.x;
    int v = (t < NBUCK) ? btot[t] : 0;
    sh[t] = v;
    __syncthreads();
    for (int off = 1; off < 256; off <<= 1) {
        int x = (t >= off) ? sh[t - off] : 0;
        __syncthreads();
        sh[t] += x;
        __syncthreads();
    }
    if (t < NBUCK) bbase[t] = sh[t] - v;
    if (t == NBUCK - 1) bbase[NBUCK] = sh[t];  // == N_EDGES
}

__global__ __launch_bounds__(256) void bin_scatter(const int* __restrict__ rows,
                                                   const int* __restrict__ cols,
                                                   const int* __restrict__ boff2,
                                                   const int* __restrict__ bbase,
                                                   int* __restrict__ binned) {
    __shared__ int cur[NBUCK];
    int t = threadIdx.x, b = blockIdx.x;
    for (int i = t; i < NBUCK; i += 256) cur[i] = bbase[i] + boff2[b * NBUCK + i];
    __syncthreads();
    int base = b * EPB;
    for (int i = t; i < EPB; i += 256) {
        int r = rows[base + i], c = cols[base + i];
        int pos = atomicAdd(&cur[r >> 9], 1);
        binned[pos] = ((r & 511) << 17) | c;  // col < 100000 < 2^17
    }
}

// Pass 5: one block per bucket. Per-(row, coltile) counts + prefix in LDS
// (produces rowptr and dinv), then scatter col into colidx so each row's
// edges are sorted by col>>15 -> spmm gathers sweep 2 MB v-tiles (L2-fit).
__global__ __launch_bounds__(256) void bucket_csr(const int* __restrict__ binned,
                                                  const int* __restrict__ bbase,
                                                  int* __restrict__ rowptr,
                                                  int* __restrict__ colidx,
                                                  float* __restrict__ dinv) {
    __shared__ int cnt[BROWS * NTILE];   // [rlocal*4 + tile]
    __shared__ int pref[BROWS * NTILE];
    __shared__ int psum[256];
    int t = threadIdx.x, bu = blockIdx.x;
    for (int i = t; i < BROWS * NTILE; i += 256) cnt[i] = 0;
    __syncthreads();
    int base = bbase[bu], end = bbase[bu + 1];
    for (int i = base + t; i < end; i += 256) {
        int v = binned[i];
        int key = ((v >> 17) << 2) | ((v & 0x1FFFF) >> 15);
        atomicAdd(&cnt[key], 1);
    }
    __syncthreads();
    // exclusive scan of 2048 counts: 8-per-thread serial + Hillis-Steele over 256
    int loc[8];
    int s0 = 0;
#pragma unroll
    for (int j = 0; j < 8; j++) {
        loc[j] = s0;
        s0 += cnt[t * 8 + j];
    }
    psum[t] = s0;
    __syncthreads();
    for (int off = 1; off < 256; off <<= 1) {
        int x = (t >= off) ? psum[t - off] : 0;
        __syncthreads();
        psum[t] += x;
        __syncthreads();
    }
    int pex = psum[t] - s0;
#pragma unroll
    for (int j = 0; j < 8; j++) pref[t * 8 + j] = pex + loc[j];
    __syncthreads();
#pragma unroll
    for (int j = 0; j < 2; j++) {
        int idx = t + j * 256;
        int grow = bu * BROWS + idx;
        if (grow < N_NODES) {
            rowptr[grow] = base + pref[idx * 4];
            int c = cnt[idx * 4] + cnt[idx * 4 + 1] + cnt[idx * 4 + 2] + cnt[idx * 4 + 3];
            dinv[grow] = 0.5f / (float)(c + 1);  // pre-halved, +1 self-loop
        } else if (grow == N_NODES) {
            rowptr[N_NODES] = N_EDGES;
        }
    }
    __syncthreads();
    for (int i = t; i < BROWS * NTILE; i += 256) pref[i] += base;  // absolute cursors
    __syncthreads();
    for (int i = base + t; i < end; i += 256) {
        int v = binned[i];
        int key = ((v >> 17) << 2) | ((v & 0x1FFFF) >> 15);
        int pos = atomicAdd(&pref[key], 1);
        colidx[pos] = v & 0x1FFFF;  // raw col
    }
}

// ---------------- weight conversion ----------------

__global__ void cvt_f2b(const float* __restrict__ a, bf16* __restrict__ b, int n) {
    int i = blockIdx.x * 256 + threadIdx.x;
    if (i < n) b[i] = (bf16)a[i];
}

__global__ void pad_w3(const float* __restrict__ W3, const float* __restrict__ b3,
                       bf16* __restrict__ W3p, float* __restrict__ b3p) {
    int i = blockIdx.x * 256 + threadIdx.x;  // over 64*256
    int r = i >> 8;
    W3p[i] = (bf16)((r < NCLASS) ? W3[(size_t)r * 256 + (i & 255)] : 0.f);
    if (i < 64) b3p[i] = (i < NCLASS) ? b3[i] : 0.f;
}

// zero the dummy gather rows (index N_NODES) in all v buffers
__global__ void zero_dummy(bf16* vAi, bf16* vA0, bf16* vA1,
                           bf16* vBi, bf16* vB0, bf16* vB1) {
    int i = threadIdx.x;
    if (i < 32) {
        vAi[(size_t)ZA + i] = (bf16)0.f;
        vA0[(size_t)ZA + i] = (bf16)0.f;
        vA1[(size_t)ZA + i] = (bf16)0.f;
    }
    if (i < 8) {
        vBi[(size_t)ZB + i] = (bf16)0.f;
        vB0[(size_t)ZB + i] = (bf16)0.f;
        vB1[(size_t)ZB + i] = (bf16)0.f;
    }
}

// ---------------- bf16 MFMA GEMM-NT, 2-phase double-buffered ----------------
// C[M,Nout] = A[M,K] @ B[Nout,K]^T + bias. A fp32 or bf16 (converted in staging).
// OUTMODE 0: bf16 out. OUTMODE 1: split outputs hA/hB (fp32, pre-halved) +
// vA0/vB0 (bf16 initial power-iteration state).

template <int BN, typename AT, bool RELU, int OUTMODE>
__global__ __launch_bounds__(256) void gemm_mfma(const AT* __restrict__ A,
                                                 const bf16* __restrict__ B,
                                                 const float* __restrict__ bias,
                                                 bf16* __restrict__ Cb,
                                                 float* __restrict__ hA,
                                                 float* __restrict__ hB,
                                                 bf16* __restrict__ vA0,
                                                 bf16* __restrict__ vB0,
                                                 int M, int K, int Nout) {
    constexpr int LDT = 40;                      // 80 B rows: 16B-aligned, 2-way banks on b128 reads
    constexpr int WTM = (BN == 128) ? 64 : 32;   // wave tile M
    constexpr int MI = WTM / 16;
    constexpr int WMC = 128 / WTM;               // waves along M
    constexpr int BG = BN / 64;
    constexpr bool AF32 = std::is_same<AT, float>::value;
    __shared__ bf16 As[2][128 * LDT];
    __shared__ bf16 Bs[2][BN * LDT];

    int tid = threadIdx.x;
    int wave = tid >> 6, lane = tid & 63;
    int waveM = wave % WMC, waveN = wave / WMC;
    int lc = lane & 15, lq = lane >> 4;

    f32x4 acc[MI][4];
#pragma unroll
    for (int i = 0; i < MI; i++)
#pragma unroll
        for (int j = 0; j < 4; j++) acc[i][j] = (f32x4){0.f, 0.f, 0.f, 0.f};

    int sr = tid >> 2;           // staging row base (0..63)
    int sc = (tid & 3) * 8;      // staging col (8 bf16)

    // staging registers (issue-early / write-late)
    float4 pa[2][2];
    bf16x8 ba[2];
    bf16x8 bb[BG];

    auto LOAD = [&](int k0) {
#pragma unroll
        for (int g = 0; g < 2; g++) {
            int grow = blockIdx.y * 128 + sr + g * 64;
            if constexpr (AF32) {
                if (grow < M) {
                    const float* ap = A + (size_t)grow * K + k0 + sc;
                    pa[g][0] = *(const float4*)ap;
                    pa[g][1] = *(const float4*)(ap + 4);
                } else {
                    pa[g][0] = (float4){0.f, 0.f, 0.f, 0.f};
                    pa[g][1] = (float4){0.f, 0.f, 0.f, 0.f};
                }
            } else {
                ba[g] = (grow < M) ? *(const bf16x8*)(A + (size_t)grow * K + k0 + sc)
                                   : (bf16x8){};
            }
        }
#pragma unroll
        for (int g = 0; g < BG; g++) {
            int brow = blockIdx.x * BN + sr + g * 64;
            bb[g] = *(const bf16x8*)(B + (size_t)brow * K + k0 + sc);
        }
    };
    auto STORE = [&](int buf) {
#pragma unroll
        for (int g = 0; g < 2; g++) {
            bf16x8 val;
            if constexpr (AF32) {
                val[0] = (bf16)pa[g][0].x; val[1] = (bf16)pa[g][0].y;
                val[2] = (bf16)pa[g][0].z; val[3] = (bf16)pa[g][0].w;
                val[4] = (bf16)pa[g][1].x; val[5] = (bf16)pa[g][1].y;
                val[6] = (bf16)pa[g][1].z; val[7] = (bf16)pa[g][1].w;
            } else {
                val = ba[g];
            }
            *(bf16x8*)&As[buf][(sr + g * 64) * LDT + sc] = val;
        }
#pragma unroll
        for (int g = 0; g < BG; g++)
            *(bf16x8*)&Bs[buf][(sr + g * 64) * LDT + sc] = bb[g];
    };

    int nt = K / 32;
    LOAD(0);
    STORE(0);
    __syncthreads();
    int cur = 0;
    for (int t = 0; t < nt; t++) {
        if (t + 1 < nt) LOAD((t + 1) * 32);   // issue next-tile loads early
        bf16x8 af[MI], bfr[4];
#pragma unroll
        for (int i = 0; i < MI; i++)
            af[i] = *(const bf16x8*)&As[cur][(waveM * WTM + i * 16 + lc) * LDT + lq * 8];
#pragma unroll
        for (int j = 0; j < 4; j++)
            bfr[j] = *(const bf16x8*)&Bs[cur][(waveN * 64 + j * 16 + lc) * LDT + lq * 8];
#pragma unroll
        for (int i = 0; i < MI; i++)
#pragma unroll
            for (int j = 0; j < 4; j++)
                acc[i][j] = __builtin_amdgcn_mfma_f32_16x16x32_bf16(af[i], bfr[j], acc[i][j], 0, 0, 0);
        if (t + 1 < nt) STORE(cur ^ 1);       // vmcnt wait lands here, after MFMAs
        __syncthreads();                      // one barrier per K-step
        cur ^= 1;
    }

    // epilogue
#pragma unroll
    for (int i = 0; i < MI; i++) {
        int row0 = blockIdx.y * 128 + waveM * WTM + i * 16 + lq * 4;
#pragma unroll
        for (int j = 0; j < 4; j++) {
            int colL = waveN * 64 + j * 16 + lc;
            int col = blockIdx.x * BN + colL;
            float bv = bias[col];
#pragma unroll
            for (int reg = 0; reg < 4; reg++) {
                int rr = row0 + reg;
                if (rr < M) {
                    float v = acc[i][j][reg] + bv;
                    if (RELU) v = v > 0.f ? v : 0.f;
                    if (OUTMODE == 0) {
                        Cb[(size_t)rr * Nout + col] = (bf16)v;
                    } else {
                        if (col < 32) {
                            hA[(size_t)rr * 32 + col] = 0.5f * v;
                            vA0[(size_t)rr * 32 + col] = (bf16)v;
                        } else if (col < NCLASS) {
                            hB[(size_t)rr * 8 + (col - 32)] = 0.5f * v;
                            vB0[(size_t)rr * 8 + (col - 32)] = (bf16)v;
                        }
                    }
                }
            }
        }
    }
}

// ---------------- class-split power-iteration SpMM ----------------
// Pass A (blocks 0..BLK_A-1): 32 classes, 64 B rows, 2 rows per wave.
// Pass B (blocks BLK_A..):    8 classes, 16 B rows (1.6 MB, L2-resident),
//                             8 rows per wave.
// Edge lists are coltile-sorted -> pass-A gathers sweep 2 MB v-tiles.

__global__ __launch_bounds__(256) void spmm_split(const bf16* __restrict__ vA,
                                                  const bf16* __restrict__ vB,
                                                  const float* __restrict__ hA,
                                                  const float* __restrict__ hB,
                                                  const int* __restrict__ rowptr,
                                                  const int* __restrict__ colidx,
                                                  const float* __restrict__ dinv,
                                                  bf16* __restrict__ oA,
                                                  bf16* __restrict__ oB,
                                                  float* __restrict__ outF,
                                                  int final_it) {
    int b = blockIdx.x;
    int lane = threadIdx.x & 63;
    if (b < BLK_A) {
        int w = b * 4 + (threadIdx.x >> 6);   // 0..49999
        int cls = lane & 31;
        int r = 2 * w + (lane >> 5);
        int s = rowptr[r], e = rowptr[r + 1];
        int d = e - s;
        int od = __shfl_xor(d, 32);
        int dmax = d > od ? d : od;
        float hv = hA[(size_t)r * 32 + cls];  // pre-halved
        float dv = dinv[r];
        float a0 = (float)vA[(size_t)r * 32 + cls];  // self-loop
        float a1 = 0.f, a2 = 0.f, a3 = 0.f, a4 = 0.f, a5 = 0.f, a6 = 0.f, a7 = 0.f;
        for (int i = 0; i < dmax; i += 8) {
#define GA(J, ACC)                                                      \
            {                                                           \
                int off = (i + J < d) ? (colidx[s + i + J] << 5) : ZA;  \
                ACC += (float)vA[(size_t)off + cls];                    \
            }
            GA(0, a0) GA(1, a1) GA(2, a2) GA(3, a3)
            GA(4, a4) GA(5, a5) GA(6, a6) GA(7, a7)
#undef GA
        }
        float res = dv * (((a0 + a1) + (a2 + a3)) + ((a4 + a5) + (a6 + a7))) + hv;
        if (final_it) outF[(size_t)r * NCLASS + cls] = res;
        else oA[(size_t)r * 32 + cls] = (bf16)res;
    } else {
        int w = (b - BLK_A) * 4 + (threadIdx.x >> 6);  // 0..12499
        int cls = lane & 7;
        int r = 8 * w + (lane >> 3);
        int s = rowptr[r], e = rowptr[r + 1];
        int d = e - s;
        int m = d;
        int x = __shfl_xor(m, 8);  m = m > x ? m : x;
        x = __shfl_xor(m, 16);     m = m > x ? m : x;
        x = __shfl_xor(m, 32);     m = m > x ? m : x;
        float hv = hB[(size_t)r * 8 + cls];   // pre-halved
        float dv = dinv[r];
        float a0 = (float)vB[(size_t)r * 8 + cls];  // self-loop
        float a1 = 0.f, a2 = 0.f, a3 = 0.f, a4 = 0.f, a5 = 0.f, a6 = 0.f, a7 = 0.f;
        for (int i = 0; i < m; i += 8) {
#define GB(J, ACC)                                                      \
            {                                                           \
                int off = (i + J < d) ? (colidx[s + i + J] << 3) : ZB;  \
                ACC += (float)vB[(size_t)off + cls];                    \
            }
            GB(0, a0) GB(1, a1) GB(2, a2) GB(3, a3)
            GB(4, a4) GB(5, a5) GB(6, a6) GB(7, a7)
#undef GB
        }
        float res = dv * (((a0 + a1) + (a2 + a3)) + ((a4 + a5) + (a6 + a7))) + hv;
        if (final_it) outF[(size_t)r * NCLASS + 32 + cls] = res;
        else oB[(size_t)r * 8 + cls] = (bf16)res;
    }
}

// ---------------- launch ----------------

extern "C" void kernel_launch(void* const* d_in, const int* in_sizes, int n_in,
                              void* d_out, int out_size, void* d_ws, size_t ws_size,
                              hipStream_t stream) {
    const float* x  = (const float*)d_in[0];
    const int*   ei = (const int*)d_in[1];
    const float* W1 = (const float*)d_in[2];
    const float* b1 = (const float*)d_in[3];
    const float* W2 = (const float*)d_in[4];
    const float* b2 = (const float*)d_in[5];
    const float* W3 = (const float*)d_in[6];
    const float* b3 = (const float*)d_in[7];
    float* out = (float*)d_out;
    const int* rows = ei;
    const int* cols = ei + N_EDGES;

    // workspace carve (bytes)
    char* p = (char*)d_ws;
    bf16* hid1 = (bf16*)p;                 p += (size_t)N_NODES * NHID * 2;       // 51.2 MB (alias: binned)
    bf16* hid2 = (bf16*)p;                 p += (size_t)N_NODES * NHID * 2;       // 51.2 MB
    float* hA  = (float*)p;                p += (size_t)N_NODES * 32 * 4;         // 12.8 MB
    float* hB  = (float*)p;                p += (size_t)N_NODES * 8 * 4;          // 3.2 MB
    bf16* vAi  = (bf16*)p;                 p += (size_t)(N_NODES + 1) * 32 * 2;   // 6.4 MB
    bf16* vA0  = (bf16*)p;                 p += (size_t)(N_NODES + 1) * 32 * 2;
    bf16* vA1  = (bf16*)p;                 p += (size_t)(N_NODES + 1) * 32 * 2;
    bf16* vBi  = (bf16*)p;                 p += (size_t)(N_NODES + 1) * 8 * 2;    // 1.6 MB
    bf16* vB0  = (bf16*)p;                 p += (size_t)(N_NODES + 1) * 8 * 2;
    bf16* vB1  = (bf16*)p;                 p += (size_t)(N_NODES + 1) * 8 * 2;
    bf16* W1b  = (bf16*)p;                 p += (size_t)NHID * NFEAT * 2;
    bf16* W2b  = (bf16*)p;                 p += (size_t)NHID * NHID * 2;
    bf16* W3p  = (bf16*)p;                 p += (size_t)64 * NHID * 2;
    float* b3p = (float*)p;                p += 64 * 4;
    int* bcnt   = (int*)p;                 p += (size_t)NPAD * 4;
    int* rowptr = (int*)p;                 p += (size_t)(NPAD + 1) * 4;
    int* boff2  = (int*)p;                 p += (size_t)N_NODES * 4;
    int* colidx = (int*)p;                 p += (size_t)(N_EDGES + 64) * 4;
    int* bsum   = (int*)p;                 p += 512 * 4;
    float* dinv = (float*)p;               p += (size_t)N_NODES * 4;

    int* btot  = bsum;          // 196 ints
    int* bbase = bsum + 256;    // 197 ints
    int* binned = (int*)hid1;   // 6.4 MB, dead before MLP starts

    // CSR build (edges end up coltile-sorted within each row)
    bin_count<<<NBLK_BIN, 256, 0, stream>>>(rows, bcnt);
    bin_scan<<<NBUCK, 256, 0, stream>>>(bcnt, boff2, btot);
    base_scan<<<1, 256, 0, stream>>>(btot, bbase);
    bin_scatter<<<NBLK_BIN, 256, 0, stream>>>(rows, cols, boff2, bbase, binned);
    bucket_csr<<<NBUCK, 256, 0, stream>>>(binned, bbase, rowptr, colidx, dinv);

    // weight conversion
    cvt_f2b<<<(NHID * NFEAT + 255) / 256, 256, 0, stream>>>(W1, W1b, NHID * NFEAT);
    cvt_f2b<<<(NHID * NHID + 255) / 256, 256, 0, stream>>>(W2, W2b, NHID * NHID);
    pad_w3<<<(64 * NHID) / 256, 256, 0, stream>>>(W3, b3, W3p, b3p);

    // MLP, full M per layer (LDS-staged double-buffered MFMA GEMM)
    {
        int M = N_NODES;
        int gy = (M + 127) / 128;
        gemm_mfma<128, float, true, 0><<<dim3(2, gy), 256, 0, stream>>>(
            x, W1b, b1, hid1, nullptr, nullptr, nullptr, nullptr, M, NFEAT, NHID);
        gemm_mfma<128, bf16, true, 0><<<dim3(2, gy), 256, 0, stream>>>(
            hid1, W2b, b2, hid2, nullptr, nullptr, nullptr, nullptr, M, NHID, NHID);
        gemm_mfma<64, bf16, false, 1><<<dim3(1, gy), 256, 0, stream>>>(
            hid2, W3p, b3p, nullptr, hA, hB, vAi, vBi, M, NHID, 64);
    }

    zero_dummy<<<1, 64, 0, stream>>>(vAi, vA0, vA1, vBi, vB0, vB1);

    // 10 power iterations, class-split (A: 32 classes, B: 8 classes), fused launch
    const bf16* sA = vAi;
    const bf16* sB = vBi;
    for (int it = 0; it < 10; it++) {
        int fin = (it == 9);
        bf16* dA = (it & 1) ? vA1 : vA0;
        bf16* dB = (it & 1) ? vB1 : vB0;
        spmm_split<<<BLK_A + BLK_B, 256, 0, stream>>>(
            sA, sB, hA, hB, rowptr, colidx, dinv, dA, dB, out, fin);
        sA = dA;
        sB = dB;
    }
}

// Round 8
// 849.906 us; speedup vs baseline: 1.7999x; 1.3575x over previous
//
#include <hip/hip_runtime.h>
#include <type_traits>

#define N_NODES 100000
#define N_EDGES 1600000
#define NFEAT 512
#define NHID 256
#define NCLASS 40
#define NPAD 100096    // 391 * 256
#define NPAD2 100352   // 196 * 512 (rowptr2 entries)

// bucket sort geometry
#define NBUCK 196     // buckets of 512 rows: (99999>>9)=195 -> 196 buckets
#define BROWS 512
#define NBLK_BIN 256
#define EPB 6250      // 256 * 6250 == 1,600,000 exactly

// padded colidx: rows padded to multiple of 4; per-bucket slack 1600
#define CDUM 1916000          // dummy 4-int segment (cols = N_NODES)
#define COLN 1916032          // colidx allocation (ints)

// class-split power iteration: 40 = 32 (pass A) + 8 (pass B)
#define ZA (N_NODES * 32)   // dummy zero-row element offset, pass A
#define ZB (N_NODES * 8)    // dummy zero-row element offset, pass B
#define BLK_A 3125          // 12,500 waves x 8 rows
#define BLK_B 391           // 1,564 waves x 64 rows (last partial)

typedef __bf16 bf16;
typedef __bf16 bf16x8 __attribute__((ext_vector_type(8)));
typedef __bf16 bf16x4 __attribute__((ext_vector_type(4)));
typedef float f32x4 __attribute__((ext_vector_type(4)));
typedef int i32x4 __attribute__((ext_vector_type(4)));

// ---------------- CSR build via 2-level counting sort ----------------

__global__ __launch_bounds__(256) void bin_count(const int* __restrict__ rows,
                                                 int* __restrict__ bcnt) {
    __shared__ int hist[NBUCK];
    int t = threadIdx.x, b = blockIdx.x;
    for (int i = t; i < NBUCK; i += 256) hist[i] = 0;
    __syncthreads();
    int base = b * EPB;
    for (int i = t; i < EPB; i += 256) atomicAdd(&hist[rows[base + i] >> 9], 1);
    __syncthreads();
    for (int i = t; i < NBUCK; i += 256) bcnt[i * NBLK_BIN + b] = hist[i];
}

__global__ __launch_bounds__(256) void bin_scan(const int* __restrict__ bcnt,
                                                int* __restrict__ boff2,
                                                int* __restrict__ btot) {
    __shared__ int sh[256];
    int t = threadIdx.x, bu = blockIdx.x;
    int v = bcnt[bu * 256 + t];
    sh[t] = v;
    __syncthreads();
    for (int off = 1; off < 256; off <<= 1) {
        int x = (t >= off) ? sh[t - off] : 0;
        __syncthreads();
        sh[t] += x;
        __syncthreads();
    }
    boff2[t * NBUCK + bu] = sh[t] - v;  // exclusive, [block][bucket] layout
    if (t == 255) btot[bu] = sh[255];
}

__global__ __launch_bounds__(256) void base_scan(const int* __restrict__ btot,
                                                 int* __restrict__ bbase) {
    __shared__ int sh[256];
    int t = threadIdx.x;
    int v = (t < NBUCK) ? btot[t] : 0;
    sh[t] = v;
    __syncthreads();
    for (int off = 1; off < 256; off <<= 1) {
        int x = (t >= off) ? sh[t - off] : 0;
        __syncthreads();
        sh[t] += x;
        __syncthreads();
    }
    if (t < NBUCK) bbase[t] = sh[t] - v;
    if (t == NBUCK - 1) bbase[NBUCK] = sh[t];  // == N_EDGES
}

__global__ __launch_bounds__(256) void bin_scatter(const int* __restrict__ rows,
                                                   const int* __restrict__ cols,
                                                   const int* __restrict__ boff2,
                                                   const int* __restrict__ bbase,
                                                   int* __restrict__ binned) {
    __shared__ int cur[NBUCK];
    int t = threadIdx.x, b = blockIdx.x;
    for (int i = t; i < NBUCK; i += 256) cur[i] = bbase[i] + boff2[b * NBUCK + i];
    __syncthreads();
    int base = b * EPB;
    for (int i = t; i < EPB; i += 256) {
        int r = rows[base + i], c = cols[base + i];
        int pos = atomicAdd(&cur[r >> 9], 1);
        binned[pos] = ((r & 511) << 17) | c;  // col < 100000 < 2^17
    }
}

// Pass 5: one block per bucket. Per-row counts + PADDED (multiple-of-4,
// 16B-aligned) prefix in LDS; produces rowptr2 (start,end) and dinv; pads
// each row's tail with dummy col N_NODES; scatters cols.
__global__ __launch_bounds__(256) void bucket_csr(const int* __restrict__ binned,
                                                  const int* __restrict__ bbase,
                                                  int2* __restrict__ rowptr2,
                                                  int* __restrict__ colidx,
                                                  float* __restrict__ dinv) {
    __shared__ int cnt[BROWS];
    __shared__ int pref[BROWS];
    __shared__ int psum[256];
    int t = threadIdx.x, bu = blockIdx.x;
    cnt[t] = 0;
    cnt[t + 256] = 0;
    __syncthreads();
    int base = bbase[bu], end = bbase[bu + 1];
    for (int i = base + t; i < end; i += 256) atomicAdd(&cnt[binned[i] >> 17], 1);
    __syncthreads();
    int c0 = cnt[2 * t], c1 = cnt[2 * t + 1];
    int p0 = (c0 + 3) & ~3, p1 = (c1 + 3) & ~3;
    psum[t] = p0 + p1;
    __syncthreads();
    for (int off = 1; off < 256; off <<= 1) {
        int x = (t >= off) ? psum[t - off] : 0;
        __syncthreads();
        psum[t] += x;
        __syncthreads();
    }
    int pex = psum[t] - (p0 + p1);
    pref[2 * t] = pex;
    pref[2 * t + 1] = pex + p0;
    __syncthreads();
    int pbase = (base & ~3) + bu * 1600;   // 4-aligned, slack-separated
#pragma unroll
    for (int j = 0; j < 2; j++) {
        int idx = t + j * 256;
        int grow = bu * BROWS + idx;
        int rc = cnt[idx];
        int st = pbase + pref[idx];
        int en = st + ((rc + 3) & ~3);
        if (grow < N_NODES) {
            rowptr2[grow] = make_int2(st, en);
            dinv[grow] = 0.5f / (float)(rc + 1);  // pre-halved, +1 self-loop
            for (int k = st + rc; k < en; k++) colidx[k] = N_NODES;  // dummy pad
        } else {
            rowptr2[grow] = make_int2(0, 0);      // grow < NPAD2 always
        }
        pref[idx] = st;  // absolute cursor
    }
    __syncthreads();
    for (int i = base + t; i < end; i += 256) {
        int v = binned[i];
        int pos = atomicAdd(&pref[v >> 17], 1);
        colidx[pos] = v & 0x1FFFF;
    }
}

// ---------------- weight conversion ----------------

__global__ void cvt_f2b(const float* __restrict__ a, bf16* __restrict__ b, int n) {
    int i = blockIdx.x * 256 + threadIdx.x;
    if (i < n) b[i] = (bf16)a[i];
}

__global__ void pad_w3(const float* __restrict__ W3, const float* __restrict__ b3,
                       bf16* __restrict__ W3p, float* __restrict__ b3p) {
    int i = blockIdx.x * 256 + threadIdx.x;  // over 64*256
    int r = i >> 8;
    W3p[i] = (bf16)((r < NCLASS) ? W3[(size_t)r * 256 + (i & 255)] : 0.f);
    if (i < 64) b3p[i] = (i < NCLASS) ? b3[i] : 0.f;
}

// zero dummy gather rows + dummy colidx segment
__global__ void zero_dummy(bf16* vAi, bf16* vA0, bf16* vA1,
                           bf16* vBi, bf16* vB0, bf16* vB1,
                           int* colidx) {
    int i = threadIdx.x;
    if (i < 32) {
        vAi[(size_t)ZA + i] = (bf16)0.f;
        vA0[(size_t)ZA + i] = (bf16)0.f;
        vA1[(size_t)ZA + i] = (bf16)0.f;
    }
    if (i < 8) {
        vBi[(size_t)ZB + i] = (bf16)0.f;
        vB0[(size_t)ZB + i] = (bf16)0.f;
        vB1[(size_t)ZB + i] = (bf16)0.f;
        colidx[CDUM + i] = N_NODES;
    }
}

// ---------------- bf16 MFMA GEMM-NT, 2-phase double-buffered ----------------

template <int BN, typename AT, bool RELU, int OUTMODE>
__global__ __launch_bounds__(256) void gemm_mfma(const AT* __restrict__ A,
                                                 const bf16* __restrict__ B,
                                                 const float* __restrict__ bias,
                                                 bf16* __restrict__ Cb,
                                                 float* __restrict__ hA,
                                                 float* __restrict__ hB,
                                                 bf16* __restrict__ vA0,
                                                 bf16* __restrict__ vB0,
                                                 int M, int K, int Nout) {
    constexpr int LDT = 40;
    constexpr int WTM = (BN == 128) ? 64 : 32;
    constexpr int MI = WTM / 16;
    constexpr int WMC = 128 / WTM;
    constexpr int BG = BN / 64;
    constexpr bool AF32 = std::is_same<AT, float>::value;
    __shared__ bf16 As[2][128 * LDT];
    __shared__ bf16 Bs[2][BN * LDT];

    int tid = threadIdx.x;
    int wave = tid >> 6, lane = tid & 63;
    int waveM = wave % WMC, waveN = wave / WMC;
    int lc = lane & 15, lq = lane >> 4;

    f32x4 acc[MI][4];
#pragma unroll
    for (int i = 0; i < MI; i++)
#pragma unroll
        for (int j = 0; j < 4; j++) acc[i][j] = (f32x4){0.f, 0.f, 0.f, 0.f};

    int sr = tid >> 2;
    int sc = (tid & 3) * 8;

    float4 pa[2][2];
    bf16x8 ba[2];
    bf16x8 bb[BG];

    auto LOAD = [&](int k0) {
#pragma unroll
        for (int g = 0; g < 2; g++) {
            int grow = blockIdx.y * 128 + sr + g * 64;
            if constexpr (AF32) {
                if (grow < M) {
                    const float* ap = A + (size_t)grow * K + k0 + sc;
                    pa[g][0] = *(const float4*)ap;
                    pa[g][1] = *(const float4*)(ap + 4);
                } else {
                    pa[g][0] = (float4){0.f, 0.f, 0.f, 0.f};
                    pa[g][1] = (float4){0.f, 0.f, 0.f, 0.f};
                }
            } else {
                ba[g] = (grow < M) ? *(const bf16x8*)(A + (size_t)grow * K + k0 + sc)
                                   : (bf16x8){};
            }
        }
#pragma unroll
        for (int g = 0; g < BG; g++) {
            int brow = blockIdx.x * BN + sr + g * 64;
            bb[g] = *(const bf16x8*)(B + (size_t)brow * K + k0 + sc);
        }
    };
    auto STORE = [&](int buf) {
#pragma unroll
        for (int g = 0; g < 2; g++) {
            bf16x8 val;
            if constexpr (AF32) {
                val[0] = (bf16)pa[g][0].x; val[1] = (bf16)pa[g][0].y;
                val[2] = (bf16)pa[g][0].z; val[3] = (bf16)pa[g][0].w;
                val[4] = (bf16)pa[g][1].x; val[5] = (bf16)pa[g][1].y;
                val[6] = (bf16)pa[g][1].z; val[7] = (bf16)pa[g][1].w;
            } else {
                val = ba[g];
            }
            *(bf16x8*)&As[buf][(sr + g * 64) * LDT + sc] = val;
        }
#pragma unroll
        for (int g = 0; g < BG; g++)
            *(bf16x8*)&Bs[buf][(sr + g * 64) * LDT + sc] = bb[g];
    };

    int nt = K / 32;
    LOAD(0);
    STORE(0);
    __syncthreads();
    int cur = 0;
    for (int t = 0; t < nt; t++) {
        if (t + 1 < nt) LOAD((t + 1) * 32);
        bf16x8 af[MI], bfr[4];
#pragma unroll
        for (int i = 0; i < MI; i++)
            af[i] = *(const bf16x8*)&As[cur][(waveM * WTM + i * 16 + lc) * LDT + lq * 8];
#pragma unroll
        for (int j = 0; j < 4; j++)
            bfr[j] = *(const bf16x8*)&Bs[cur][(waveN * 64 + j * 16 + lc) * LDT + lq * 8];
#pragma unroll
        for (int i = 0; i < MI; i++)
#pragma unroll
            for (int j = 0; j < 4; j++)
                acc[i][j] = __builtin_amdgcn_mfma_f32_16x16x32_bf16(af[i], bfr[j], acc[i][j], 0, 0, 0);
        if (t + 1 < nt) STORE(cur ^ 1);
        __syncthreads();
        cur ^= 1;
    }

#pragma unroll
    for (int i = 0; i < MI; i++) {
        int row0 = blockIdx.y * 128 + waveM * WTM + i * 16 + lq * 4;
#pragma unroll
        for (int j = 0; j < 4; j++) {
            int colL = waveN * 64 + j * 16 + lc;
            int col = blockIdx.x * BN + colL;
            float bv = bias[col];
#pragma unroll
            for (int reg = 0; reg < 4; reg++) {
                int rr = row0 + reg;
                if (rr < M) {
                    float v = acc[i][j][reg] + bv;
                    if (RELU) v = v > 0.f ? v : 0.f;
                    if (OUTMODE == 0) {
                        Cb[(size_t)rr * Nout + col] = (bf16)v;
                    } else {
                        if (col < 32) {
                            hA[(size_t)rr * 32 + col] = 0.5f * v;
                            vA0[(size_t)rr * 32 + col] = (bf16)v;
                        } else if (col < NCLASS) {
                            hB[(size_t)rr * 8 + (col - 32)] = 0.5f * v;
                            vB0[(size_t)rr * 8 + (col - 32)] = (bf16)v;
                        }
                    }
                }
            }
        }
    }
}

// ---------------- wide-load class-split power-iteration SpMM ----------------
// Pass A: 32 classes, lane=4 cls (8B), 8 lanes/row, 8 rows/wave.
//   One gather instr = 8 edges; colidx via one int4 per 4 edges, prefetched.
// Pass B: 8 classes, lane=whole row (16B), 64 rows/wave.
//   One gather instr = 64 edges.

__global__ __launch_bounds__(256) void spmm_split(const bf16* __restrict__ vA,
                                                  const bf16* __restrict__ vB,
                                                  const float* __restrict__ hA,
                                                  const float* __restrict__ hB,
                                                  const int2* __restrict__ rowptr2,
                                                  const int* __restrict__ colidx,
                                                  const float* __restrict__ dinv,
                                                  bf16* __restrict__ oA,
                                                  bf16* __restrict__ oB,
                                                  float* __restrict__ outF,
                                                  int final_it) {
    int b = blockIdx.x;
    int lane = threadIdx.x & 63;
    const int* cdum = colidx + CDUM;
    if (b < BLK_A) {
        int w = b * 4 + (threadIdx.x >> 6);   // 0..12499
        int sub = lane & 7;
        int r = w * 8 + (lane >> 3);          // 0..99999
        int2 se = rowptr2[r];
        int sx = se.x, d = se.y - se.x;       // padded degree, multiple of 4
        int m = d;
        int x = __shfl_xor(m, 8);  m = m > x ? m : x;
        x = __shfl_xor(m, 16);     m = m > x ? m : x;
        x = __shfl_xor(m, 32);     m = m > x ? m : x;
        float4 hv = *(const float4*)(hA + (size_t)r * 32 + sub * 4);  // pre-halved
        float dv = dinv[r];
        bf16x4 sv = *(const bf16x4*)(vA + (size_t)r * 32 + sub * 4);  // self-loop
        float a0 = (float)sv[0], a1 = (float)sv[1], a2 = (float)sv[2], a3 = (float)sv[3];
        i32x4 cc = *(const i32x4*)(d > 0 ? colidx + sx : cdum);
        for (int i = 0; i < m; i += 4) {
            const int* np = (i + 4 < d) ? (colidx + sx + i + 4) : cdum;
            i32x4 cn = *(const i32x4*)np;     // prefetch next batch
            bf16x4 g0 = *(const bf16x4*)(vA + (size_t)cc[0] * 32 + sub * 4);
            bf16x4 g1 = *(const bf16x4*)(vA + (size_t)cc[1] * 32 + sub * 4);
            bf16x4 g2 = *(const bf16x4*)(vA + (size_t)cc[2] * 32 + sub * 4);
            bf16x4 g3 = *(const bf16x4*)(vA + (size_t)cc[3] * 32 + sub * 4);
            a0 += ((float)g0[0] + (float)g1[0]) + ((float)g2[0] + (float)g3[0]);
            a1 += ((float)g0[1] + (float)g1[1]) + ((float)g2[1] + (float)g3[1]);
            a2 += ((float)g0[2] + (float)g1[2]) + ((float)g2[2] + (float)g3[2]);
            a3 += ((float)g0[3] + (float)g1[3]) + ((float)g2[3] + (float)g3[3]);
            cc = cn;
        }
        float r0 = dv * a0 + hv.x;
        float r1 = dv * a1 + hv.y;
        float r2 = dv * a2 + hv.z;
        float r3 = dv * a3 + hv.w;
        if (final_it) {
            *(float4*)(outF + (size_t)r * NCLASS + sub * 4) = (float4){r0, r1, r2, r3};
        } else {
            bf16x4 o;
            o[0] = (bf16)r0; o[1] = (bf16)r1; o[2] = (bf16)r2; o[3] = (bf16)r3;
            *(bf16x4*)(oA + (size_t)r * 32 + sub * 4) = o;
        }
    } else {
        int w = (b - BLK_A) * 4 + (threadIdx.x >> 6);  // 0..1563
        int r = w * 64 + lane;                          // 0..100095
        int rh = (r < N_NODES) ? r : N_NODES;           // v: dummy zero row
        int rz = (r < N_NODES) ? r : 0;                 // h/dinv: clamp to 0
        int2 se = rowptr2[r];                           // (0,0) for r>=N_NODES
        int sx = se.x, d = se.y - se.x;
        int m = d;
#pragma unroll
        for (int off = 1; off < 64; off <<= 1) {
            int x = __shfl_xor(m, off);
            m = m > x ? m : x;
        }
        float4 h0 = *(const float4*)(hB + (size_t)rz * 8);
        float4 h1 = *(const float4*)(hB + (size_t)rz * 8 + 4);
        float dv = dinv[rz];
        bf16x8 sv = *(const bf16x8*)(vB + (size_t)rh * 8);  // self-loop
        float a[8];
#pragma unroll
        for (int k = 0; k < 8; k++) a[k] = (float)sv[k];
        i32x4 cc = *(const i32x4*)(d > 0 ? colidx + sx : cdum);
        for (int i = 0; i < m; i += 4) {
            const int* np = (i + 4 < d) ? (colidx + sx + i + 4) : cdum;
            i32x4 cn = *(const i32x4*)np;
            bf16x8 g0 = *(const bf16x8*)(vB + (size_t)cc[0] * 8);
            bf16x8 g1 = *(const bf16x8*)(vB + (size_t)cc[1] * 8);
            bf16x8 g2 = *(const bf16x8*)(vB + (size_t)cc[2] * 8);
            bf16x8 g3 = *(const bf16x8*)(vB + (size_t)cc[3] * 8);
#pragma unroll
            for (int k = 0; k < 8; k++)
                a[k] += ((float)g0[k] + (float)g1[k]) + ((float)g2[k] + (float)g3[k]);
            cc = cn;
        }
        if (r < N_NODES) {
            float res[8];
            res[0] = dv * a[0] + h0.x; res[1] = dv * a[1] + h0.y;
            res[2] = dv * a[2] + h0.z; res[3] = dv * a[3] + h0.w;
            res[4] = dv * a[4] + h1.x; res[5] = dv * a[5] + h1.y;
            res[6] = dv * a[6] + h1.z; res[7] = dv * a[7] + h1.w;
            if (final_it) {
                *(float4*)(outF + (size_t)r * NCLASS + 32) = (float4){res[0], res[1], res[2], res[3]};
                *(float4*)(outF + (size_t)r * NCLASS + 36) = (float4){res[4], res[5], res[6], res[7]};
            } else {
                bf16x8 o;
#pragma unroll
                for (int k = 0; k < 8; k++) o[k] = (bf16)res[k];
                *(bf16x8*)(oB + (size_t)r * 8) = o;
            }
        }
    }
}

// ---------------- launch ----------------

extern "C" void kernel_launch(void* const* d_in, const int* in_sizes, int n_in,
                              void* d_out, int out_size, void* d_ws, size_t ws_size,
                              hipStream_t stream) {
    const float* x  = (const float*)d_in[0];
    const int*   ei = (const int*)d_in[1];
    const float* W1 = (const float*)d_in[2];
    const float* b1 = (const float*)d_in[3];
    const float* W2 = (const float*)d_in[4];
    const float* b2 = (const float*)d_in[5];
    const float* W3 = (const float*)d_in[6];
    const float* b3 = (const float*)d_in[7];
    float* out = (float*)d_out;
    const int* rows = ei;
    const int* cols = ei + N_EDGES;

    // workspace carve (bytes)
    char* p = (char*)d_ws;
    bf16* hid1 = (bf16*)p;                 p += (size_t)N_NODES * NHID * 2;       // 51.2 MB (alias: binned)
    bf16* hid2 = (bf16*)p;                 p += (size_t)N_NODES * NHID * 2;       // 51.2 MB
    float* hA  = (float*)p;                p += (size_t)N_NODES * 32 * 4;         // 12.8 MB
    float* hB  = (float*)p;                p += (size_t)N_NODES * 8 * 4;          // 3.2 MB
    bf16* vAi  = (bf16*)p;                 p += (size_t)(N_NODES + 1) * 32 * 2;   // 6.4 MB
    bf16* vA0  = (bf16*)p;                 p += (size_t)(N_NODES + 1) * 32 * 2;
    bf16* vA1  = (bf16*)p;                 p += (size_t)(N_NODES + 1) * 32 * 2;
    bf16* vBi  = (bf16*)p;                 p += (size_t)(N_NODES + 1) * 8 * 2;    // 1.6 MB
    bf16* vB0  = (bf16*)p;                 p += (size_t)(N_NODES + 1) * 8 * 2;
    bf16* vB1  = (bf16*)p;                 p += (size_t)(N_NODES + 1) * 8 * 2;
    bf16* W1b  = (bf16*)p;                 p += (size_t)NHID * NFEAT * 2;
    bf16* W2b  = (bf16*)p;                 p += (size_t)NHID * NHID * 2;
    bf16* W3p  = (bf16*)p;                 p += (size_t)64 * NHID * 2;
    float* b3p = (float*)p;                p += 64 * 4;
    int* bcnt    = (int*)p;                p += (size_t)NPAD * 4;
    int2* rowptr2 = (int2*)p;              p += (size_t)NPAD2 * 8;
    int* boff2   = (int*)p;                p += (size_t)N_NODES * 4;
    int* colidx  = (int*)p;                p += (size_t)COLN * 4;                 // 7.7 MB (padded)
    int* bsum    = (int*)p;                p += 512 * 4;
    float* dinv  = (float*)p;              p += (size_t)N_NODES * 4;

    int* btot  = bsum;          // 196 ints
    int* bbase = bsum + 256;    // 197 ints
    int* binned = (int*)hid1;   // 6.4 MB, dead before MLP starts

    // CSR build (rows padded to multiple of 4, 16B-aligned segments)
    bin_count<<<NBLK_BIN, 256, 0, stream>>>(rows, bcnt);
    bin_scan<<<NBUCK, 256, 0, stream>>>(bcnt, boff2, btot);
    base_scan<<<1, 256, 0, stream>>>(btot, bbase);
    bin_scatter<<<NBLK_BIN, 256, 0, stream>>>(rows, cols, boff2, bbase, binned);
    bucket_csr<<<NBUCK, 256, 0, stream>>>(binned, bbase, rowptr2, colidx, dinv);

    // weight conversion
    cvt_f2b<<<(NHID * NFEAT + 255) / 256, 256, 0, stream>>>(W1, W1b, NHID * NFEAT);
    cvt_f2b<<<(NHID * NHID + 255) / 256, 256, 0, stream>>>(W2, W2b, NHID * NHID);
    pad_w3<<<(64 * NHID) / 256, 256, 0, stream>>>(W3, b3, W3p, b3p);

    // MLP, full M per layer (LDS-staged double-buffered MFMA GEMM)
    {
        int M = N_NODES;
        int gy = (M + 127) / 128;
        gemm_mfma<128, float, true, 0><<<dim3(2, gy), 256, 0, stream>>>(
            x, W1b, b1, hid1, nullptr, nullptr, nullptr, nullptr, M, NFEAT, NHID);
        gemm_mfma<128, bf16, true, 0><<<dim3(2, gy), 256, 0, stream>>>(
            hid1, W2b, b2, hid2, nullptr, nullptr, nullptr, nullptr, M, NHID, NHID);
        gemm_mfma<64, bf16, false, 1><<<dim3(1, gy), 256, 0, stream>>>(
            hid2, W3p, b3p, nullptr, hA, hB, vAi, vBi, M, NHID, 64);
    }

    zero_dummy<<<1, 64, 0, stream>>>(vAi, vA0, vA1, vBi, vB0, vB1, colidx);

    // 10 power iterations, wide-load class-split (A: 32 cls, B: 8 cls)
    const bf16* sA = vAi;
    const bf16* sB = vBi;
    for (int it = 0; it < 10; it++) {
        int fin = (it == 9);
        bf16* dA = (it & 1) ? vA1 : vA0;
        bf16* dB = (it & 1) ? vB1 : vB0;
        spmm_split<<<BLK_A + BLK_B, 256, 0, stream>>>(
            sA, sB, hA, hB, rowptr2, colidx, dinv, dA, dB, out, fin);
        sA = dA;
        sB = dB;
    }
}

// Round 9
// 804.953 us; speedup vs baseline: 1.9005x; 1.0558x over previous
//
#include <hip/hip_runtime.h>
#include <type_traits>

#define N_NODES 100000
#define N_EDGES 1600000
#define NFEAT 512
#define NHID 256
#define NCLASS 40
#define NPAD 100096    // 391 * 256
#define NPAD2 100352   // 196 * 512 (rowptr2 entries)

// bucket sort geometry
#define NBUCK 196     // buckets of 512 rows: (99999>>9)=195 -> 196 buckets
#define BROWS 512
#define NBLK_BIN 256
#define EPB 6250      // 256 * 6250 == 1,600,000 exactly

// padded colidx: rows padded to multiple of 4; per-bucket slack 1600
#define CDUM 1916000          // dummy 4-int segment (cols = N_NODES)
#define COLN 1916032          // colidx allocation (ints)

// class-split power iteration: 40 = 32 (pass A) + 8 (pass B)
#define ZA (N_NODES * 32)   // dummy zero-row element offset, pass A
#define ZB (N_NODES * 8)    // dummy zero-row element offset, pass B
#define BLK_A 1563          // 6,250 waves x 16 rows (last block tail-guarded)
#define BLK_B 391           // 1,564 waves x 64 rows (last partial)

typedef __bf16 bf16;
typedef __bf16 bf16x8 __attribute__((ext_vector_type(8)));
typedef __bf16 bf16x4 __attribute__((ext_vector_type(4)));
typedef float f32x4 __attribute__((ext_vector_type(4)));
typedef int i32x4 __attribute__((ext_vector_type(4)));

// ---------------- CSR build via 2-level counting sort ----------------

__global__ __launch_bounds__(256) void bin_count(const int* __restrict__ rows,
                                                 int* __restrict__ bcnt) {
    __shared__ int hist[NBUCK];
    int t = threadIdx.x, b = blockIdx.x;
    for (int i = t; i < NBUCK; i += 256) hist[i] = 0;
    __syncthreads();
    int base = b * EPB;
    for (int i = t; i < EPB; i += 256) atomicAdd(&hist[rows[base + i] >> 9], 1);
    __syncthreads();
    for (int i = t; i < NBUCK; i += 256) bcnt[i * NBLK_BIN + b] = hist[i];
}

__global__ __launch_bounds__(256) void bin_scan(const int* __restrict__ bcnt,
                                                int* __restrict__ boff2,
                                                int* __restrict__ btot) {
    __shared__ int sh[256];
    int t = threadIdx.x, bu = blockIdx.x;
    int v = bcnt[bu * 256 + t];
    sh[t] = v;
    __syncthreads();
    for (int off = 1; off < 256; off <<= 1) {
        int x = (t >= off) ? sh[t - off] : 0;
        __syncthreads();
        sh[t] += x;
        __syncthreads();
    }
    boff2[t * NBUCK + bu] = sh[t] - v;  // exclusive, [block][bucket] layout
    if (t == 255) btot[bu] = sh[255];
}

__global__ __launch_bounds__(256) void base_scan(const int* __restrict__ btot,
                                                 int* __restrict__ bbase) {
    __shared__ int sh[256];
    int t = threadIdx.x;
    int v = (t < NBUCK) ? btot[t] : 0;
    sh[t] = v;
    __syncthreads();
    for (int off = 1; off < 256; off <<= 1) {
        int x = (t >= off) ? sh[t - off] : 0;
        __syncthreads();
        sh[t] += x;
        __syncthreads();
    }
    if (t < NBUCK) bbase[t] = sh[t] - v;
    if (t == NBUCK - 1) bbase[NBUCK] = sh[t];  // == N_EDGES
}

__global__ __launch_bounds__(256) void bin_scatter(const int* __restrict__ rows,
                                                   const int* __restrict__ cols,
                                                   const int* __restrict__ boff2,
                                                   const int* __restrict__ bbase,
                                                   int* __restrict__ binned) {
    __shared__ int cur[NBUCK];
    int t = threadIdx.x, b = blockIdx.x;
    for (int i = t; i < NBUCK; i += 256) cur[i] = bbase[i] + boff2[b * NBUCK + i];
    __syncthreads();
    int base = b * EPB;
    for (int i = t; i < EPB; i += 256) {
        int r = rows[base + i], c = cols[base + i];
        int pos = atomicAdd(&cur[r >> 9], 1);
        binned[pos] = ((r & 511) << 17) | c;  // col < 100000 < 2^17
    }
}

// Pass 5: one block per bucket. Per-row counts + PADDED (multiple-of-4,
// 16B-aligned) prefix in LDS; produces rowptr2 (start,end) and dinv; pads
// each row's tail with dummy col N_NODES; scatters cols.
__global__ __launch_bounds__(256) void bucket_csr(const int* __restrict__ binned,
                                                  const int* __restrict__ bbase,
                                                  int2* __restrict__ rowptr2,
                                                  int* __restrict__ colidx,
                                                  float* __restrict__ dinv) {
    __shared__ int cnt[BROWS];
    __shared__ int pref[BROWS];
    __shared__ int psum[256];
    int t = threadIdx.x, bu = blockIdx.x;
    cnt[t] = 0;
    cnt[t + 256] = 0;
    __syncthreads();
    int base = bbase[bu], end = bbase[bu + 1];
    for (int i = base + t; i < end; i += 256) atomicAdd(&cnt[binned[i] >> 17], 1);
    __syncthreads();
    int c0 = cnt[2 * t], c1 = cnt[2 * t + 1];
    int p0 = (c0 + 3) & ~3, p1 = (c1 + 3) & ~3;
    psum[t] = p0 + p1;
    __syncthreads();
    for (int off = 1; off < 256; off <<= 1) {
        int x = (t >= off) ? psum[t - off] : 0;
        __syncthreads();
        psum[t] += x;
        __syncthreads();
    }
    int pex = psum[t] - (p0 + p1);
    pref[2 * t] = pex;
    pref[2 * t + 1] = pex + p0;
    __syncthreads();
    int pbase = (base & ~3) + bu * 1600;   // 4-aligned, slack-separated
#pragma unroll
    for (int j = 0; j < 2; j++) {
        int idx = t + j * 256;
        int grow = bu * BROWS + idx;
        int rc = cnt[idx];
        int st = pbase + pref[idx];
        int en = st + ((rc + 3) & ~3);
        if (grow < N_NODES) {
            rowptr2[grow] = make_int2(st, en);
            dinv[grow] = 0.5f / (float)(rc + 1);  // pre-halved, +1 self-loop
            for (int k = st + rc; k < en; k++) colidx[k] = N_NODES;  // dummy pad
        } else {
            rowptr2[grow] = make_int2(0, 0);      // grow < NPAD2 always
        }
        pref[idx] = st;  // absolute cursor
    }
    __syncthreads();
    for (int i = base + t; i < end; i += 256) {
        int v = binned[i];
        int pos = atomicAdd(&pref[v >> 17], 1);
        colidx[pos] = v & 0x1FFFF;
    }
}

// ---------------- weight conversion ----------------

__global__ void cvt_f2b(const float* __restrict__ a, bf16* __restrict__ b, int n) {
    int i = blockIdx.x * 256 + threadIdx.x;
    if (i < n) b[i] = (bf16)a[i];
}

__global__ void pad_w3(const float* __restrict__ W3, const float* __restrict__ b3,
                       bf16* __restrict__ W3p, float* __restrict__ b3p) {
    int i = blockIdx.x * 256 + threadIdx.x;  // over 64*256
    int r = i >> 8;
    W3p[i] = (bf16)((r < NCLASS) ? W3[(size_t)r * 256 + (i & 255)] : 0.f);
    if (i < 64) b3p[i] = (i < NCLASS) ? b3[i] : 0.f;
}

// zero dummy gather rows + dummy colidx segment
__global__ void zero_dummy(bf16* vAi, bf16* vA0, bf16* vA1,
                           bf16* vBi, bf16* vB0, bf16* vB1,
                           int* colidx) {
    int i = threadIdx.x;
    if (i < 32) {
        vAi[(size_t)ZA + i] = (bf16)0.f;
        vA0[(size_t)ZA + i] = (bf16)0.f;
        vA1[(size_t)ZA + i] = (bf16)0.f;
    }
    if (i < 8) {
        vBi[(size_t)ZB + i] = (bf16)0.f;
        vB0[(size_t)ZB + i] = (bf16)0.f;
        vB1[(size_t)ZB + i] = (bf16)0.f;
        colidx[CDUM + i] = N_NODES;
    }
}

// ---------------- bf16 MFMA GEMM-NT, 2-set deep-pipelined ----------------
// Iteration t: STORE tile t+1 (regs loaded 2 iterations ago -> vmcnt drained),
// re-LOAD that set with tile t+3, COMPUTE tile t from LDS, barrier.

template <int BN, typename AT, bool RELU, int OUTMODE>
__global__ __launch_bounds__(256) void gemm_mfma(const AT* __restrict__ A,
                                                 const bf16* __restrict__ B,
                                                 const float* __restrict__ bias,
                                                 bf16* __restrict__ Cb,
                                                 float* __restrict__ hA,
                                                 float* __restrict__ hB,
                                                 bf16* __restrict__ vA0,
                                                 bf16* __restrict__ vB0,
                                                 int M, int K, int Nout) {
    constexpr int LDT = 40;
    constexpr int WTM = (BN == 128) ? 64 : 32;
    constexpr int MI = WTM / 16;
    constexpr int WMC = 128 / WTM;
    constexpr int BG = BN / 64;
    constexpr bool AF32 = std::is_same<AT, float>::value;
    __shared__ bf16 As[2][128 * LDT];
    __shared__ bf16 Bs[2][BN * LDT];

    int tid = threadIdx.x;
    int wave = tid >> 6, lane = tid & 63;
    int waveM = wave % WMC, waveN = wave / WMC;
    int lc = lane & 15, lq = lane >> 4;

    f32x4 acc[MI][4];
#pragma unroll
    for (int i = 0; i < MI; i++)
#pragma unroll
        for (int j = 0; j < 4; j++) acc[i][j] = (f32x4){0.f, 0.f, 0.f, 0.f};

    int sr = tid >> 2;
    int sc = (tid & 3) * 8;

    // two staging register sets (static names, rule #20)
    float4 paE[2][2], paO[2][2];
    bf16x8 baE[2], baO[2];
    bf16x8 bbE[BG], bbO[BG];

    auto LOAD = [&](int k0, float4 (&pa)[2][2], bf16x8 (&ba)[2], bf16x8 (&bb)[BG]) {
#pragma unroll
        for (int g = 0; g < 2; g++) {
            int grow = blockIdx.y * 128 + sr + g * 64;
            if constexpr (AF32) {
                if (grow < M) {
                    const float* ap = A + (size_t)grow * K + k0 + sc;
                    pa[g][0] = *(const float4*)ap;
                    pa[g][1] = *(const float4*)(ap + 4);
                } else {
                    pa[g][0] = (float4){0.f, 0.f, 0.f, 0.f};
                    pa[g][1] = (float4){0.f, 0.f, 0.f, 0.f};
                }
            } else {
                ba[g] = (grow < M) ? *(const bf16x8*)(A + (size_t)grow * K + k0 + sc)
                                   : (bf16x8){};
            }
        }
#pragma unroll
        for (int g = 0; g < BG; g++) {
            int brow = blockIdx.x * BN + sr + g * 64;
            bb[g] = *(const bf16x8*)(B + (size_t)brow * K + k0 + sc);
        }
    };
    auto STORE = [&](int buf, float4 (&pa)[2][2], bf16x8 (&ba)[2], bf16x8 (&bb)[BG]) {
#pragma unroll
        for (int g = 0; g < 2; g++) {
            bf16x8 val;
            if constexpr (AF32) {
                val[0] = (bf16)pa[g][0].x; val[1] = (bf16)pa[g][0].y;
                val[2] = (bf16)pa[g][0].z; val[3] = (bf16)pa[g][0].w;
                val[4] = (bf16)pa[g][1].x; val[5] = (bf16)pa[g][1].y;
                val[6] = (bf16)pa[g][1].z; val[7] = (bf16)pa[g][1].w;
            } else {
                val = ba[g];
            }
            *(bf16x8*)&As[buf][(sr + g * 64) * LDT + sc] = val;
        }
#pragma unroll
        for (int g = 0; g < BG; g++)
            *(bf16x8*)&Bs[buf][(sr + g * 64) * LDT + sc] = bb[g];
    };
    auto COMPUTE = [&](int cb) {
        bf16x8 af[MI], bfr[4];
#pragma unroll
        for (int i = 0; i < MI; i++)
            af[i] = *(const bf16x8*)&As[cb][(waveM * WTM + i * 16 + lc) * LDT + lq * 8];
#pragma unroll
        for (int j = 0; j < 4; j++)
            bfr[j] = *(const bf16x8*)&Bs[cb][(waveN * 64 + j * 16 + lc) * LDT + lq * 8];
#pragma unroll
        for (int i = 0; i < MI; i++)
#pragma unroll
            for (int j = 0; j < 4; j++)
                acc[i][j] = __builtin_amdgcn_mfma_f32_16x16x32_bf16(af[i], bfr[j], acc[i][j], 0, 0, 0);
    };

    int nt = K / 32;   // 16 or 8, always even and > 2
    // prologue: buf0 <- tile0; setE <- tile1 (in flight); setO <- tile2 (in flight)
    LOAD(0, paE, baE, bbE);
    STORE(0, paE, baE, bbE);
    LOAD(32, paE, baE, bbE);
    LOAD(64, paO, baO, bbO);
    __syncthreads();
    for (int t = 0; t < nt; t += 2) {
        // even iter t: store tile t+1 (setE), refill setE <- tile t+3, compute tile t (buf0)
        STORE(1, paE, baE, bbE);
        if (t + 3 < nt) LOAD((t + 3) * 32, paE, baE, bbE);
        COMPUTE(0);
        __syncthreads();
        // odd iter t+1: store tile t+2 (setO), refill setO <- tile t+4, compute tile t+1 (buf1)
        if (t + 2 < nt) STORE(0, paO, baO, bbO);
        if (t + 4 < nt) LOAD((t + 4) * 32, paO, baO, bbO);
        COMPUTE(1);
        __syncthreads();
    }

    // epilogue
#pragma unroll
    for (int i = 0; i < MI; i++) {
        int row0 = blockIdx.y * 128 + waveM * WTM + i * 16 + lq * 4;
#pragma unroll
        for (int j = 0; j < 4; j++) {
            int colL = waveN * 64 + j * 16 + lc;
            int col = blockIdx.x * BN + colL;
            float bv = bias[col];
#pragma unroll
            for (int reg = 0; reg < 4; reg++) {
                int rr = row0 + reg;
                if (rr < M) {
                    float v = acc[i][j][reg] + bv;
                    if (RELU) v = v > 0.f ? v : 0.f;
                    if (OUTMODE == 0) {
                        Cb[(size_t)rr * Nout + col] = (bf16)v;
                    } else {
                        if (col < 32) {
                            hA[(size_t)rr * 32 + col] = 0.5f * v;
                            vA0[(size_t)rr * 32 + col] = (bf16)v;
                        } else if (col < NCLASS) {
                            hB[(size_t)rr * 8 + (col - 32)] = 0.5f * v;
                            vB0[(size_t)rr * 8 + (col - 32)] = (bf16)v;
                        }
                    }
                }
            }
        }
    }
}

// ---------------- wide-load pipelined class-split SpMM ----------------
// Pass A: 32 classes, lane=8 cls (16B), 4 lanes/row, 16 rows/wave.
// Pass B: 8 classes, lane=whole row (16B), 64 rows/wave.
// Both: indices prefetched 2 batches ahead; gathers for batch k+1 issued
// before batch k is accumulated (2-deep pipeline, unrolled x2).

__global__ __launch_bounds__(256) void spmm_split(const bf16* __restrict__ vA,
                                                  const bf16* __restrict__ vB,
                                                  const float* __restrict__ hA,
                                                  const float* __restrict__ hB,
                                                  const int2* __restrict__ rowptr2,
                                                  const int* __restrict__ colidx,
                                                  const float* __restrict__ dinv,
                                                  bf16* __restrict__ oA,
                                                  bf16* __restrict__ oB,
                                                  float* __restrict__ outF,
                                                  int final_it) {
    int b = blockIdx.x;
    int lane = threadIdx.x & 63;
    const int* cdum = colidx + CDUM;
    if (b < BLK_A) {
        int w = b * 4 + (threadIdx.x >> 6);   // wave 0..6251
        int sub = lane & 3;
        int r = w * 16 + (lane >> 2);         // 16 rows per wave
        if (r >= N_NODES) return;             // uniform for tail waves
        int2 se = rowptr2[r];
        int sx = se.x, d = se.y - se.x;       // padded degree, multiple of 4
        int m = d;
#pragma unroll
        for (int off = 4; off < 64; off <<= 1) {
            int x = __shfl_xor(m, off);
            m = m > x ? m : x;
        }
        float4 hv0 = *(const float4*)(hA + (size_t)r * 32 + sub * 8);      // pre-halved
        float4 hv1 = *(const float4*)(hA + (size_t)r * 32 + sub * 8 + 4);
        float dv = dinv[r];
        bf16x8 sv = *(const bf16x8*)(vA + (size_t)r * 32 + sub * 8);  // self-loop
        float a[8];
#pragma unroll
        for (int k = 0; k < 8; k++) a[k] = (float)sv[k];
        // pipeline primer: idx batches 0 and 1; gathers for batch 0
        i32x4 cc = *(const i32x4*)(d > 0 ? colidx + sx : cdum);
        i32x4 cn = *(const i32x4*)(4 < d ? colidx + sx + 4 : cdum);
        bf16x8 G0 = *(const bf16x8*)(vA + (size_t)cc[0] * 32 + sub * 8);
        bf16x8 G1 = *(const bf16x8*)(vA + (size_t)cc[1] * 32 + sub * 8);
        bf16x8 G2 = *(const bf16x8*)(vA + (size_t)cc[2] * 32 + sub * 8);
        bf16x8 G3 = *(const bf16x8*)(vA + (size_t)cc[3] * 32 + sub * 8);
        int m8 = (m + 7) & ~7;
        for (int i = 0; i < m8; i += 8) {
            // half 1: prefetch idx i+8; issue gathers(batch i+4); accumulate batch i
            i32x4 ci8 = *(const i32x4*)((i + 8 < d) ? colidx + sx + i + 8 : cdum);
            bf16x8 H0 = *(const bf16x8*)(vA + (size_t)cn[0] * 32 + sub * 8);
            bf16x8 H1 = *(const bf16x8*)(vA + (size_t)cn[1] * 32 + sub * 8);
            bf16x8 H2 = *(const bf16x8*)(vA + (size_t)cn[2] * 32 + sub * 8);
            bf16x8 H3 = *(const bf16x8*)(vA + (size_t)cn[3] * 32 + sub * 8);
#pragma unroll
            for (int k = 0; k < 8; k++)
                a[k] += ((float)G0[k] + (float)G1[k]) + ((float)G2[k] + (float)G3[k]);
            // half 2: prefetch idx i+12; issue gathers(batch i+8); accumulate batch i+4
            cn = *(const i32x4*)((i + 12 < d) ? colidx + sx + i + 12 : cdum);
            G0 = *(const bf16x8*)(vA + (size_t)ci8[0] * 32 + sub * 8);
            G1 = *(const bf16x8*)(vA + (size_t)ci8[1] * 32 + sub * 8);
            G2 = *(const bf16x8*)(vA + (size_t)ci8[2] * 32 + sub * 8);
            G3 = *(const bf16x8*)(vA + (size_t)ci8[3] * 32 + sub * 8);
#pragma unroll
            for (int k = 0; k < 8; k++)
                a[k] += ((float)H0[k] + (float)H1[k]) + ((float)H2[k] + (float)H3[k]);
        }
        float res[8];
        res[0] = dv * a[0] + hv0.x; res[1] = dv * a[1] + hv0.y;
        res[2] = dv * a[2] + hv0.z; res[3] = dv * a[3] + hv0.w;
        res[4] = dv * a[4] + hv1.x; res[5] = dv * a[5] + hv1.y;
        res[6] = dv * a[6] + hv1.z; res[7] = dv * a[7] + hv1.w;
        if (final_it) {
            *(float4*)(outF + (size_t)r * NCLASS + sub * 8) = (float4){res[0], res[1], res[2], res[3]};
            *(float4*)(outF + (size_t)r * NCLASS + sub * 8 + 4) = (float4){res[4], res[5], res[6], res[7]};
        } else {
            bf16x8 o;
#pragma unroll
            for (int k = 0; k < 8; k++) o[k] = (bf16)res[k];
            *(bf16x8*)(oA + (size_t)r * 32 + sub * 8) = o;
        }
    } else {
        int w = (b - BLK_A) * 4 + (threadIdx.x >> 6);  // 0..1563
        int r = w * 64 + lane;                          // 0..100095 (< NPAD2)
        int rz = (r < N_NODES) ? r : 0;                 // h/dinv/v: clamp to 0
        int2 se = rowptr2[r];                           // (0,0) for r>=N_NODES
        int sx = se.x, d = se.y - se.x;
        int m = d;
#pragma unroll
        for (int off = 1; off < 64; off <<= 1) {
            int x = __shfl_xor(m, off);
            m = m > x ? m : x;
        }
        float4 h0 = *(const float4*)(hB + (size_t)rz * 8);
        float4 h1 = *(const float4*)(hB + (size_t)rz * 8 + 4);
        float dv = dinv[rz];
        bf16x8 sv = *(const bf16x8*)(vB + (size_t)rz * 8);  // self-loop
        float a[8];
#pragma unroll
        for (int k = 0; k < 8; k++) a[k] = (float)sv[k];
        i32x4 cc = *(const i32x4*)(d > 0 ? colidx + sx : cdum);
        i32x4 cn = *(const i32x4*)(4 < d ? colidx + sx + 4 : cdum);
        bf16x8 G0 = *(const bf16x8*)(vB + (size_t)cc[0] * 8);
        bf16x8 G1 = *(const bf16x8*)(vB + (size_t)cc[1] * 8);
        bf16x8 G2 = *(const bf16x8*)(vB + (size_t)cc[2] * 8);
        bf16x8 G3 = *(const bf16x8*)(vB + (size_t)cc[3] * 8);
        int m8 = (m + 7) & ~7;
        for (int i = 0; i < m8; i += 8) {
            i32x4 ci8 = *(const i32x4*)((i + 8 < d) ? colidx + sx + i + 8 : cdum);
            bf16x8 H0 = *(const bf16x8*)(vB + (size_t)cn[0] * 8);
            bf16x8 H1 = *(const bf16x8*)(vB + (size_t)cn[1] * 8);
            bf16x8 H2 = *(const bf16x8*)(vB + (size_t)cn[2] * 8);
            bf16x8 H3 = *(const bf16x8*)(vB + (size_t)cn[3] * 8);
#pragma unroll
            for (int k = 0; k < 8; k++)
                a[k] += ((float)G0[k] + (float)G1[k]) + ((float)G2[k] + (float)G3[k]);
            cn = *(const i32x4*)((i + 12 < d) ? colidx + sx + i + 12 : cdum);
            G0 = *(const bf16x8*)(vB + (size_t)ci8[0] * 8);
            G1 = *(const bf16x8*)(vB + (size_t)ci8[1] * 8);
            G2 = *(const bf16x8*)(vB + (size_t)ci8[2] * 8);
            G3 = *(const bf16x8*)(vB + (size_t)ci8[3] * 8);
#pragma unroll
            for (int k = 0; k < 8; k++)
                a[k] += ((float)H0[k] + (float)H1[k]) + ((float)H2[k] + (float)H3[k]);
        }
        if (r < N_NODES) {
            float res[8];
            res[0] = dv * a[0] + h0.x; res[1] = dv * a[1] + h0.y;
            res[2] = dv * a[2] + h0.z; res[3] = dv * a[3] + h0.w;
            res[4] = dv * a[4] + h1.x; res[5] = dv * a[5] + h1.y;
            res[6] = dv * a[6] + h1.z; res[7] = dv * a[7] + h1.w;
            if (final_it) {
                *(float4*)(outF + (size_t)r * NCLASS + 32) = (float4){res[0], res[1], res[2], res[3]};
                *(float4*)(outF + (size_t)r * NCLASS + 36) = (float4){res[4], res[5], res[6], res[7]};
            } else {
                bf16x8 o;
#pragma unroll
                for (int k = 0; k < 8; k++) o[k] = (bf16)res[k];
                *(bf16x8*)(oB + (size_t)r * 8) = o;
            }
        }
    }
}

// ---------------- launch ----------------

extern "C" void kernel_launch(void* const* d_in, const int* in_sizes, int n_in,
                              void* d_out, int out_size, void* d_ws, size_t ws_size,
                              hipStream_t stream) {
    const float* x  = (const float*)d_in[0];
    const int*   ei = (const int*)d_in[1];
    const float* W1 = (const float*)d_in[2];
    const float* b1 = (const float*)d_in[3];
    const float* W2 = (const float*)d_in[4];
    const float* b2 = (const float*)d_in[5];
    const float* W3 = (const float*)d_in[6];
    const float* b3 = (const float*)d_in[7];
    float* out = (float*)d_out;
    const int* rows = ei;
    const int* cols = ei + N_EDGES;

    // workspace carve (bytes)
    char* p = (char*)d_ws;
    bf16* hid1 = (bf16*)p;                 p += (size_t)N_NODES * NHID * 2;       // 51.2 MB (alias: binned)
    bf16* hid2 = (bf16*)p;                 p += (size_t)N_NODES * NHID * 2;       // 51.2 MB
    float* hA  = (float*)p;                p += (size_t)N_NODES * 32 * 4;         // 12.8 MB
    float* hB  = (float*)p;                p += (size_t)N_NODES * 8 * 4;          // 3.2 MB
    bf16* vAi  = (bf16*)p;                 p += (size_t)(N_NODES + 1) * 32 * 2;   // 6.4 MB
    bf16* vA0  = (bf16*)p;                 p += (size_t)(N_NODES + 1) * 32 * 2;
    bf16* vA1  = (bf16*)p;                 p += (size_t)(N_NODES + 1) * 32 * 2;
    bf16* vBi  = (bf16*)p;                 p += (size_t)(N_NODES + 1) * 8 * 2;    // 1.6 MB
    bf16* vB0  = (bf16*)p;                 p += (size_t)(N_NODES + 1) * 8 * 2;
    bf16* vB1  = (bf16*)p;                 p += (size_t)(N_NODES + 1) * 8 * 2;
    bf16* W1b  = (bf16*)p;                 p += (size_t)NHID * NFEAT * 2;
    bf16* W2b  = (bf16*)p;                 p += (size_t)NHID * NHID * 2;
    bf16* W3p  = (bf16*)p;                 p += (size_t)64 * NHID * 2;
    float* b3p = (float*)p;                p += 64 * 4;
    int* bcnt    = (int*)p;                p += (size_t)NPAD * 4;
    int2* rowptr2 = (int2*)p;              p += (size_t)NPAD2 * 8;
    int* boff2   = (int*)p;                p += (size_t)N_NODES * 4;
    int* colidx  = (int*)p;                p += (size_t)COLN * 4;                 // 7.7 MB (padded)
    int* bsum    = (int*)p;                p += 512 * 4;
    float* dinv  = (float*)p;              p += (size_t)N_NODES * 4;

    int* btot  = bsum;          // 196 ints
    int* bbase = bsum + 256;    // 197 ints
    int* binned = (int*)hid1;   // 6.4 MB, dead before MLP starts

    // CSR build (rows padded to multiple of 4, 16B-aligned segments)
    bin_count<<<NBLK_BIN, 256, 0, stream>>>(rows, bcnt);
    bin_scan<<<NBUCK, 256, 0, stream>>>(bcnt, boff2, btot);
    base_scan<<<1, 256, 0, stream>>>(btot, bbase);
    bin_scatter<<<NBLK_BIN, 256, 0, stream>>>(rows, cols, boff2, bbase, binned);
    bucket_csr<<<NBUCK, 256, 0, stream>>>(binned, bbase, rowptr2, colidx, dinv);

    // weight conversion
    cvt_f2b<<<(NHID * NFEAT + 255) / 256, 256, 0, stream>>>(W1, W1b, NHID * NFEAT);
    cvt_f2b<<<(NHID * NHID + 255) / 256, 256, 0, stream>>>(W2, W2b, NHID * NHID);
    pad_w3<<<(64 * NHID) / 256, 256, 0, stream>>>(W3, b3, W3p, b3p);

    // MLP, full M per layer (LDS double-buffered, 2-set deep-pipelined MFMA GEMM)
    {
        int M = N_NODES;
        int gy = (M + 127) / 128;
        gemm_mfma<128, float, true, 0><<<dim3(2, gy), 256, 0, stream>>>(
            x, W1b, b1, hid1, nullptr, nullptr, nullptr, nullptr, M, NFEAT, NHID);
        gemm_mfma<128, bf16, true, 0><<<dim3(2, gy), 256, 0, stream>>>(
            hid1, W2b, b2, hid2, nullptr, nullptr, nullptr, nullptr, M, NHID, NHID);
        gemm_mfma<64, bf16, false, 1><<<dim3(1, gy), 256, 0, stream>>>(
            hid2, W3p, b3p, nullptr, hA, hB, vAi, vBi, M, NHID, 64);
    }

    zero_dummy<<<1, 64, 0, stream>>>(vAi, vA0, vA1, vBi, vB0, vB1, colidx);

    // 10 power iterations, wide-load pipelined class-split (A: 32 cls, B: 8 cls)
    const bf16* sA = vAi;
    const bf16* sB = vBi;
    for (int it = 0; it < 10; it++) {
        int fin = (it == 9);
        bf16* dA = (it & 1) ? vA1 : vA0;
        bf16* dB = (it & 1) ? vB1 : vB0;
        spmm_split<<<BLK_A + BLK_B, 256, 0, stream>>>(
            sA, sB, hA, hB, rowptr2, colidx, dinv, dA, dB, out, fin);
        sA = dA;
        sB = dB;
    }
}